// Round 7
// baseline (2062.688 us; speedup 1.0000x reference)
//
#include <hip/hip_runtime.h>

#define NPATH 15
#define TOTCG 615
#define TOTD  179

// path tables: PATHS enumeration order of the reference
constexpr int PI_[NPATH]    = {0,0,0,1,1,1,1,1,1,2,2,2,2,2,2};
constexpr int PF_[NPATH]    = {0,1,2,0,1,1,1,2,2,0,1,1,2,2,2};
constexpr int PO_[NPATH]    = {0,1,2,1,0,1,2,1,2,2,1,2,0,1,2};
constexpr int PSLOT_[NPATH] = {0,0,0,1,1,2,1,3,2,3,4,4,2,5,5};
// cumulative size (2i+1)(2f+1)(2o+1)
constexpr int CGOFF_[NPATH] = {0,1,10,35,44,53,80,125,170,245,270,315,390,415,490};
// cumulative size (2i+1)(2o+1)  (D entries)
constexpr int EBASE_[NPATH] = {0,1,4,9,18,21,30,45,54,69,94,109,134,139,154};
// cumulative size (2i+1)(2f+1)  (complex CG tasks)
constexpr int CB_[NPATH]    = {0,1,4,9,12,21,30,39,54,69,74,89,104,129,154};
// acc register layout: cumsum of (2o+1)
constexpr int PACC_[NPATH]  = {0,1,4,9,12,13,16,21,24,29,34,37,42,43,46}; // total 51
// st-concat layout base: O=0 -> S*40 ; O=1 -> 120+S*120 ; O=2 -> 840+S*200
constexpr int STBASE_[NPATH]= {0,120,840,240,40,360,1040,480,1240,1440,600,1640,80,720,1840};

// ws float offsets
#define OFF_CG 0
#define OFF_CW 1024
#define OFF_CB 1280
#define OFF_DT 1536
// int offsets (CSR)
#define ICNT 4096
#define IROW 45056
#define ICUR 86016
#define IEID 126976
// float offsets (big arrays)
#define FH   608256
#define FOUTS 2208256

__device__ inline float sspf(float v){
  float a = fabsf(v);
  return fmaxf(v, 0.f) + log1pf(expf(-a)) - 0.6931471805599453f;
}

__device__ inline double dfact_(int n){ double r=1.0; for(int i=2;i<=n;++i) r*=(double)i; return r; }

__device__ double cgc_(int j1,int j2,int j3,int m1,int m2,int m3){
  double pre = sqrt((2.0*j3+1.0)*dfact_(j1+j2-j3)*dfact_(j1-j2+j3)*dfact_(-j1+j2+j3)/dfact_(j1+j2+j3+1));
  pre *= sqrt(dfact_(j3+m3)*dfact_(j3-m3)*dfact_(j1-m1)*dfact_(j1+m1)*dfact_(j2-m2)*dfact_(j2+m2));
  double s=0.0;
  for(int k=0;k<=j1+j2-j3;++k){
    int d1=j1+j2-j3-k, d2=j1-m1-k, d3=j2+m2-k, d4=j3-j2+m1+k, d5=j3-j1-m2+k;
    if(d1<0||d2<0||d3<0||d4<0||d5<0) continue;
    double den = dfact_(k)*dfact_(d1)*dfact_(d2)*dfact_(d3)*dfact_(d4)*dfact_(d5);
    s += ((k&1)? -1.0:1.0)/den;
  }
  return pre*s;
}

// ---- K0: CG tables (exact replica of _cg_real), D-table, collapsed head linear ----
__global__ __launch_bounds__(256) void k_setup(const float* __restrict__ d2w, const float* __restrict__ d2b,
                        const float* __restrict__ d3w, const float* __restrict__ d3b,
                        float* __restrict__ ws){
  __shared__ double sC[TOTCG], sRe[TOTCG], sIm[TOTCG];
  __shared__ double sUr[35], sUi[35];
  const int tid = threadIdx.x;
  for (int t=tid; t<TOTCG; t+=256) sC[t]=0.0;
  if (tid==0){
    for (int t=0;t<35;t++){ sUr[t]=0.0; sUi[t]=0.0; }
    const double s2 = 0.70710678118654752440;
    sUr[0] = 1.0; // l=0
    for (int l=1;l<=2;l++){
      const int off = (l==1)?1:10;
      const int n = 2*l+1;
      sUr[off + l*n + l] = 1.0;
      for (int m=1;m<=l;m++){
        double sg = (m&1)? -1.0:1.0;
        sUr[off + (l+m)*n + (l+m)] = sg*s2;
        sUi[off + (l+m)*n + (l-m)] = sg*s2;
        sUr[off + (l-m)*n + (l+m)] = s2;
        sUi[off + (l-m)*n + (l-m)] = -s2;
      }
    }
  }
  __syncthreads();
  // phase A: complex-basis CG values
  for (int t=tid; t<179; t+=256){
    int p=0;
    for (int q=1;q<NPATH;q++) if (t>=CB_[q]) p=q;
    const int j1=PI_[p], j2=PF_[p], j3=PO_[p];
    const int n2=2*j2+1, n3=2*j3+1;
    const int loc = t - CB_[p];
    const int i1 = loc/n2, i2 = loc%n2;
    const int m1=i1-j1, m2=i2-j2, m3=m1+m2;
    if (m3>=-j3 && m3<=j3)
      sC[CGOFF_[p] + (i1*n2+i2)*n3 + (m3+j3)] = cgc_(j1,j2,j3,m1,m2,m3);
  }
  __syncthreads();
  // phase C: real transform
  for (int t=tid; t<TOTCG; t+=256){
    int p=0;
    for (int q=1;q<NPATH;q++) if (t>=CGOFF_[q]) p=q;
    const int j1=PI_[p], j2=PF_[p], j3=PO_[p];
    const int n1=2*j1+1, n2=2*j2+1, n3=2*j3+1;
    const int loc = t - CGOFF_[p];
    const int Cc = loc % n3;
    const int Bb = (loc/n3) % n2;
    const int A  = loc/(n3*n2);
    const int u1o = (j1==0)?0:((j1==1)?1:10);
    const int u2o = (j2==0)?0:((j2==1)?1:10);
    const int u3o = (j3==0)?0:((j3==1)?1:10);
    double sre=0.0, sim=0.0;
    for (int a=0;a<n1;a++){
      const double u1r = sUr[u1o + a*n1 + A], u1i = sUi[u1o + a*n1 + A];
      if (u1r==0.0 && u1i==0.0) continue;
      for (int b=0;b<n2;b++){
        const double u2r = sUr[u2o + b*n2 + Bb], u2i = sUi[u2o + b*n2 + Bb];
        if (u2r==0.0 && u2i==0.0) continue;
        const double qr = u1r*u2r - u1i*u2i;
        const double qi = u1r*u2i + u1i*u2r;
        const double* cp = &sC[CGOFF_[p] + (a*n2+b)*n3];
        for (int cidx=0;cidx<n3;cidx++){
          const double v = cp[cidx];
          if (v==0.0) continue;
          const double u3r = sUr[u3o + cidx*n3 + Cc], u3i = -sUi[u3o + cidx*n3 + Cc];
          sre += v*(qr*u3r - qi*u3i);
          sim += v*(qr*u3i + qi*u3r);
        }
      }
    }
    sRe[t]=sre; sIm[t]=sim;
  }
  __syncthreads();
  // phase D: per-path imag/real choice, write to ws
  if (tid < NPATH){
    const int p=tid;
    const int sz = ((p==NPATH-1)? TOTCG : CGOFF_[p+1]) - CGOFF_[p];
    double mxr=0.0, mxi=0.0;
    for (int t=0;t<sz;t++){
      mxr = fmax(mxr, fabs(sRe[CGOFF_[p]+t]));
      mxi = fmax(mxi, fabs(sIm[CGOFF_[p]+t]));
    }
    const bool useim = mxi > mxr;
    for (int t=0;t<sz;t++)
      ws[OFF_CG + CGOFF_[p]+t] = (float)(useim? sIm[CGOFF_[p]+t] : sRe[CGOFF_[p]+t]);
  }
  if (tid==16){
    int2* dt = (int2*)(ws + OFF_DT);
    int e=0;
    for (int p=0;p<NPATH;p++){
      const int i=PI_[p], f=PF_[p], o=PO_[p];
      const int n2=2*f+1, n3=2*o+1;
      for (int mi=0;mi<2*i+1;mi++)
        for (int k=0;k<n3;k++)
          dt[e++] = make_int2(CGOFF_[p] + mi*n2*n3 + k, n2 | (n3<<8) | ((f*f)<<16));
    }
  }
  if (tid<250){
    float acc=0.f;
    for (int k=0;k<150;k++) acc += d3w[k]*d2w[k*250+tid];
    ws[OFF_CW+tid]=acc;
  }
  if (tid==255){
    float acc = d3b[0];
    for (int k=0;k<150;k++) acc += d3w[k]*d2b[k];
    ws[OFF_CB]=acc;
  }
}

// ---- K1: h = x @ lin1_w.T + b ----
__global__ __launch_bounds__(256) void k_embed(const float* __restrict__ x, const float* __restrict__ w,
                       const float* __restrict__ b, float* __restrict__ h, int N){
  const int idx = blockIdx.x*256 + threadIdx.x;
  if (idx >= N*40) return;
  const int n = idx/40, c = idx - n*40;
  float acc = b[c];
  const float* xr = x + (size_t)n*20;
  const float* wr = w + c*20;
  #pragma unroll
  for (int k=0;k<20;k++) acc += xr[k]*wr[k];
  h[idx] = acc;
}

// ---- CSR build: histogram, scan, scatter ----
__global__ __launch_bounds__(256) void k_cnt(const int* __restrict__ ei, int* __restrict__ cnt, int E){
  const int e = blockIdx.x*256 + threadIdx.x;
  if (e < E) atomicAdd(&cnt[ei[E+e]], 1);
}

__global__ __launch_bounds__(256) void k_scan(const int* __restrict__ cnt, int* __restrict__ rowstart,
                                              int* __restrict__ cursor, int N){
  __shared__ int part[256];
  const int tid = threadIdx.x;
  const int per = (N+255)/256;
  const int base = tid*per;
  int s=0;
  for (int i=0;i<per;i++){ const int idx=base+i; if (idx<N) s+=cnt[idx]; }
  part[tid]=s;
  __syncthreads();
  if (tid==0){
    int run=0;
    for (int i=0;i<256;i++){ const int t=part[i]; part[i]=run; run+=t; }
    rowstart[N]=run;
  }
  __syncthreads();
  int run=part[tid];
  for (int i=0;i<per;i++){
    const int idx=base+i;
    if (idx<N){ rowstart[idx]=run; cursor[idx]=run; run+=cnt[idx]; }
  }
}

__global__ __launch_bounds__(256) void k_scat(const int* __restrict__ ei, int* __restrict__ cursor,
                                              int* __restrict__ eids, int E){
  const int e = blockIdx.x*256 + threadIdx.x;
  if (e < E){ const int pos = atomicAdd(&cursor[ei[E+e]], 1); eids[pos]=e; }
}

// ---- K2: fused conv1 (gather) + node transform. ONE WAVE per node, LDS-resident weights. ----
__global__ __launch_bounds__(64) void k_c1w(
    const int* __restrict__ ei, const float* __restrict__ ea,
    const int* __restrict__ rowstart, const int* __restrict__ eids,
    const float* __restrict__ rw1, const float* __restrict__ rb1,
    const float* __restrict__ rw2, const float* __restrict__ rb2,
    const float* __restrict__ h,
    const float* __restrict__ w2g, const float* __restrict__ b20,
    const float* __restrict__ w3g, const float* __restrict__ b30,
    float* __restrict__ outs){
  __shared__ float sRw1T[36*13];   // [task t=l*12+j][bb], row pad 13 -> conflict-free
  __shared__ float sRb1c[36];
  __shared__ float s_h1[36];
  __shared__ float sbuf[360];
  __shared__ float a9[360];
  const int n = blockIdx.x;
  const int lane = threadIdx.x;
  const int c = lane;
  const int r0 = rowstart[n], r1 = rowstart[n+1];
  // stage radial weights once
  for (int u=lane; u<432; u+=64){
    const int t=u/12, bb=u-(u/12)*12;
    const int l=t/12, j=t-(t/12)*12;
    sRw1T[t*13+bb] = rw1[l*144 + bb*12 + j];
  }
  if (lane<36) sRb1c[lane]=rb1[lane];
  float acc[9];
  #pragma unroll
  for (int m=0;m<9;m++) acc[m]=0.f;
  // hoist edge-invariant per-channel weights (reused across ~12 edges)
  float W36[36], base0=0.f, base1=0.f, base2=0.f;
  if (c<40){
    base0=rb2[c]; base1=rb2[40+c]; base2=rb2[80+c];
    #pragma unroll
    for (int t=0;t<36;t++) W36[t]=rw2[t*40+c];
  }
  __syncthreads();
  for (int eb = r0; eb < r1; ++eb){
    const int e = eids[eb];
    const int src = ei[e];
    const float ax=ea[3*e], ay=ea[3*e+1], az=ea[3*e+2];
    const float r = sqrtf(ax*ax+ay*ay+az*az+1e-12f);
    const float inv = 1.f/r;
    const float X=ax*inv, Yv=ay*inv, Z=az*inv;
    if (lane < 36){
      float g[12];
      const float t = r*(11.f/5.f);
      #pragma unroll
      for (int bb=0;bb<12;bb++){ const float d=t-(float)bb; g[bb]=expf(-d*d); }
      float a = sRb1c[lane];
      #pragma unroll
      for (int bb=0;bb<12;bb++) a += g[bb]*sRw1T[lane*13+bb];
      s_h1[lane] = fmaxf(a, 0.f);
    }
    __syncthreads();
    if (c<40){
      float w0=base0, w1=base1, w2=base2;
      #pragma unroll
      for (int j=0;j<12;j++){
        w0 += s_h1[j]    * W36[j];
        w1 += s_h1[12+j] * W36[12+j];
        w2 += s_h1[24+j] * W36[24+j];
      }
      const float hv = h[(size_t)src*40+c];
      acc[0] += hv*w0*0.28209479f;
      const float f1 = hv*w1;
      acc[1]+=f1*(0.48860251f*Yv); acc[2]+=f1*(0.48860251f*Z); acc[3]+=f1*(0.48860251f*X);
      const float f2 = hv*w2;
      acc[4]+=f2*(1.09254843f*X*Yv); acc[5]+=f2*(1.09254843f*Yv*Z);
      acc[6]+=f2*(0.31539157f*(3.f*Z*Z-1.f));
      acc[7]+=f2*(1.09254843f*X*Z); acc[8]+=f2*(0.54627422f*(X*X-Yv*Yv));
    }
    __syncthreads();
  }
  if (c<40){
    #pragma unroll
    for (int m=0;m<9;m++) sbuf[m*40+c]=acc[m];
  }
  __syncthreads();
  // norms per channel
  if (lane<40){
    const int cc=lane;
    const float v0=sbuf[cc];
    sbuf[cc]=v0/(fabsf(v0)+1e-8f);
    float s1=0.f;
    #pragma unroll
    for (int mm=1;mm<4;mm++){ const float v=sbuf[mm*40+cc]; s1+=v*v; }
    const float i1=1.f/(sqrtf(s1)+1e-8f);
    #pragma unroll
    for (int mm=1;mm<4;mm++) sbuf[mm*40+cc]*=i1;
    float s2=0.f;
    #pragma unroll
    for (int mm=4;mm<9;mm++){ const float v=sbuf[mm*40+cc]; s2+=v*v; }
    const float i2=1.f/(sqrtf(s2)+1e-8f);
    #pragma unroll
    for (int mm=4;mm<9;mm++) sbuf[mm*40+cc]*=i2;
  }
  __syncthreads();
  // lin2: 360 outputs (m,o)
  for (int u=lane; u<360; u+=64){
    const int m=u/40, o=u-(u/40)*40;
    const int l=(m==0)?0:((m<4)?1:2);
    const float* wr = w2g + l*1600 + o*40;
    const float* sp = sbuf + m*40;
    float a=0.f;
    for (int c2=0;c2<40;c2++) a+=sp[c2]*wr[c2];
    a9[u]=a;
  }
  __syncthreads();
  // nonlin
  if (lane<40){
    const int o=lane;
    const float a0 = sspf(a9[o]+b20[o]);
    const float n1=sqrtf(a9[40+o]*a9[40+o]+a9[80+o]*a9[80+o]+a9[120+o]*a9[120+o]+1e-12f);
    const float sc1=sspf(n1)/(n1+1e-8f);
    float s2=1e-12f;
    #pragma unroll
    for (int mm=4;mm<9;mm++) s2+=a9[mm*40+o]*a9[mm*40+o];
    const float n2=sqrtf(s2);
    const float sc2=sspf(n2)/(n2+1e-8f);
    a9[o]=a0;
    #pragma unroll
    for (int mm=1;mm<4;mm++) a9[mm*40+o]*=sc1;
    #pragma unroll
    for (int mm=4;mm<9;mm++) a9[mm*40+o]*=sc2;
  }
  __syncthreads();
  // lin3 + write
  float* op = outs + (size_t)n*360;
  for (int u=lane; u<360; u+=64){
    const int m=u/40, o=u-(u/40)*40;
    const int l=(m==0)?0:((m<4)?1:2);
    const float* wr = w3g + l*1600 + o*40;
    const float* sp = a9 + m*40;
    float b=0.f;
    for (int c2=0;c2<40;c2++) b+=sp[c2]*wr[c2];
    if (m==0) b+=b30[o];
    op[u]=b;
  }
}

// ---- K3: fused conv2 (gather) + head. 4 ca-nodes per 256-thread block, one WAVE each. ----
// Shared LDS tables (sW/sB/cgs), wave-private scratch, barrier-free edge loop.
template<int P>
__device__ inline void do_path4(const float* sB, const float* sW,
                               const float* sh1, const float* sD, const float* xi, int c,
                               float* acc){
  constexpr int I = PI_[P], O = PO_[P];
  constexpr int NO = 2*O+1;
  float wp = sB[c*17+P];
  #pragma unroll
  for (int j=0;j<12;j++) wp += sh1[P*12+j]*sW[c*181 + P*12+j];
  float tk[NO];
  #pragma unroll
  for (int k=0;k<NO;k++) tk[k]=0.f;
  #pragma unroll
  for (int mi=0;mi<2*I+1;mi++){
    const float xv = xi[I*I+mi];
    #pragma unroll
    for (int k=0;k<NO;k++) tk[k] += sD[EBASE_[P] + mi*NO + k]*xv;
  }
  #pragma unroll
  for (int k=0;k<NO;k++) acc[PACC_[P]+k] += tk[k]*wp;
}

template<int P>
__device__ inline void st_write(float* dstw, const float* acc, int c){
  constexpr int O = PO_[P];
  constexpr int NO = 2*O+1;
  #pragma unroll
  for (int k=0;k<NO;k++) dstw[STBASE_[P]+k*40+c] = acc[PACC_[P]+k];
}

__global__ __launch_bounds__(256,4) void k_c2w(
    const int* __restrict__ ei, const float* __restrict__ ea,
    const int* __restrict__ rowstart, const int* __restrict__ eids,
    const float* __restrict__ rw1, const float* __restrict__ rb1,
    const float* __restrict__ rw2, const float* __restrict__ rb2,
    const float* __restrict__ outs, const float* __restrict__ cgws, const int2* __restrict__ dtab,
    const float* __restrict__ w40, const float* __restrict__ b40,
    const float* __restrict__ w41, const float* __restrict__ w42,
    const float* __restrict__ d1w, const float* __restrict__ d1b,
    const float* __restrict__ cw, const float* __restrict__ cbp,
    float* __restrict__ out, int NCAv){
  // U: edge phase [sW 7240 | sB 680 | cgs 616] ; head phase: 4x stb[2040]
  __shared__ float U[8536];
  // S: per-wave 380f: edge phase h1[0,180) D[180,364) Y[364,376); head: v1[0,120) v2[120,320) h0[320,360)
  __shared__ float S[1520];
  const int wv = threadIdx.x>>6, lane = threadIdx.x&63, tid = threadIdx.x;
  const int c = lane;
  float* sW = U;
  float* sB = U+7240;
  float* cgs = U+7920;
  for (int u=tid; u<7200; u+=256){ sW[(u%40)*181 + u/40] = rw2[u]; }
  for (int u=tid; u<600;  u+=256){ sB[(u%40)*17  + u/40] = rb2[u]; }
  for (int u=tid; u<615;  u+=256)  cgs[u]=cgws[u];
  __syncthreads();
  const int ca = blockIdx.x*4 + wv;
  const bool okw = ca < NCAv;
  float* s_h1 = S + wv*380;
  float* s_D  = s_h1 + 180;
  float* s_Y  = s_h1 + 364;
  float acc[51];
  #pragma unroll
  for (int i=0;i<51;i++) acc[i]=0.f;
  if (okw){
    const int n = ca*4;
    const int r0 = rowstart[n], r1 = rowstart[n+1];
    for (int eb = r0; eb < r1; ++eb){
      const int e = eids[eb];
      const int src = ei[e];
      const float ax=ea[3*e], ay=ea[3*e+1], az=ea[3*e+2];
      const float r = sqrtf(ax*ax+ay*ay+az*az+1e-12f);
      const float inv = 1.f/r;
      const float X=ax*inv, Yv=ay*inv, Z=az*inv;
      if (lane==0){
        s_Y[0]=0.28209479f;
        s_Y[1]=0.48860251f*Yv; s_Y[2]=0.48860251f*Z; s_Y[3]=0.48860251f*X;
        s_Y[4]=1.09254843f*X*Yv; s_Y[5]=1.09254843f*Yv*Z;
        s_Y[6]=0.31539157f*(3.f*Z*Z-1.f);
        s_Y[7]=1.09254843f*X*Z; s_Y[8]=0.54627422f*(X*X-Yv*Yv);
      }
      if (lane < 60){
        float g[12];
        const float tt = r*(11.f/10.f);
        #pragma unroll
        for (int bb=0;bb<12;bb++){ const float d=tt-(float)bb; g[bb]=expf(-d*d); }
        #pragma unroll
        for (int rr=0;rr<3;rr++){
          const int t = rr*60 + lane;
          const int p = t/12, j = t - (t/12)*12;
          float a = rb1[t];
          #pragma unroll
          for (int bb=0;bb<12;bb++) a += g[bb]*rw1[p*144 + bb*12 + j];
          s_h1[t] = fmaxf(a, 0.f);
        }
      }
      __builtin_amdgcn_wave_barrier();   // intra-wave LDS in program order; hint only
      #pragma unroll
      for (int rr=0;rr<3;rr++){
        const int t = rr*64 + lane;
        if (t < TOTD){
          const int2 dd = dtab[t];
          const int basei = dd.x;
          const int cntv = dd.y & 0xff, str=(dd.y>>8)&0xff, yb=dd.y>>16;
          float a=0.f;
          for (int q=0;q<cntv;q++) a += cgs[basei+q*str]*s_Y[yb+q];
          s_D[t]=a;
        }
      }
      __builtin_amdgcn_wave_barrier();
      if (c<40){
        float xi[9];
        const float* xb = outs + (size_t)src*360 + c;
        #pragma unroll
        for (int mm=0;mm<9;mm++) xi[mm]=xb[mm*40];
#define DP(P) do_path4<P>(sB,sW,s_h1,s_D,xi,c,acc)
        DP(0);DP(1);DP(2);DP(3);DP(4);DP(5);DP(6);DP(7);DP(8);DP(9);DP(10);DP(11);DP(12);DP(13);DP(14);
#undef DP
      }
    }
  }
  __syncthreads();   // all waves done with U tables; reuse region for head tiles
  float* stb = U + wv*2040;
  float* v1s = S + wv*380;
  float* v2s = v1s + 120;
  float* h0s = v1s + 320;
  if (okw){
    if (c<40){
#define SW(P) st_write<P>(stb, acc, c)
      SW(0);SW(1);SW(2);SW(3);SW(4);SW(5);SW(6);SW(7);SW(8);SW(9);SW(10);SW(11);SW(12);SW(13);SW(14);
#undef SW
    }
    __builtin_amdgcn_wave_barrier();
    float* st0 = stb;
    float* st1 = stb+120;
    float* st2 = stb+840;
    // norms: 240 (s,cc) tasks
    for (int t=lane; t<240; t+=64){
      const int s = t/40, cc = t - (t/40)*40;
      float a0=st1[s*120+cc], a1=st1[s*120+40+cc], a2=st1[s*120+80+cc];
      const float i1 = 1.f/(sqrtf(a0*a0+a1*a1+a2*a2)+1e-8f);
      st1[s*120+cc]=a0*i1; st1[s*120+40+cc]=a1*i1; st1[s*120+80+cc]=a2*i1;
      float ss=0.f;
      #pragma unroll
      for (int k=0;k<5;k++){ const float v=st2[s*200+k*40+cc]; ss+=v*v; }
      const float i2 = 1.f/(sqrtf(ss)+1e-8f);
      #pragma unroll
      for (int k=0;k<5;k++) st2[s*200+k*40+cc]*=i2;
    }
    __builtin_amdgcn_wave_barrier();
    for (int t=lane; t<200; t+=64){
      const int o=t/5, k=t-(t/5)*5;
      float a=0.f;
      for (int s=0;s<6;s++){
        const float* sp = st2 + s*200 + k*40;
        const float* wr = w42 + o*240 + s*40;
        #pragma unroll
        for (int cc=0;cc<40;cc++) a += sp[cc]*wr[cc];
      }
      v2s[t]=a;
    }
    for (int t=lane; t<120; t+=64){
      const int o=t/3, k=t-(t/3)*3;
      float a=0.f;
      for (int s=0;s<6;s++){
        const float* sp = st1 + s*120 + k*40;
        const float* wr = w41 + o*240 + s*40;
        #pragma unroll
        for (int cc=0;cc<40;cc++) a += sp[cc]*wr[cc];
      }
      v1s[t]=a;
    }
    if (lane < 40){
      float a = b40[lane];
      const float* wr = w40 + lane*120;
      for (int C=0;C<120;C++) a += st0[C]*wr[C];
      h0s[lane] = sspf(a);
    }
    __builtin_amdgcn_wave_barrier();
    float* orow = out + (size_t)ca*321;
    if (lane < 40){
      const int o=lane;
      const float q0=v1s[o*3],q1=v1s[o*3+1],q2=v1s[o*3+2];
      const float nn=sqrtf(q0*q0+q1*q1+q2*q2+1e-12f);
      const float sc=sspf(nn)/(nn+1e-8f);
      orow[1+o*3]=q0*sc; orow[2+o*3]=q1*sc; orow[3+o*3]=q2*sc;
      // out2 gate for the same o
      float q[5]; float ss=1e-12f;
      #pragma unroll
      for (int k=0;k<5;k++){ q[k]=v2s[o*5+k]; ss+=q[k]*q[k]; }
      const float n2=sqrtf(ss);
      const float sc2=sspf(n2)/(n2+1e-8f);
      #pragma unroll
      for (int k=0;k<5;k++) orow[121+o*5+k]=q[k]*sc2;
    }
    // collapsed MLP: 250 hidden, wave-reduce
    float contrib=0.f;
    for (int t=lane; t<250; t+=64){
      float a=d1b[t];
      const float* wr=d1w+t*40;
      #pragma unroll
      for (int cc=0;cc<40;cc++) a += h0s[cc]*wr[cc];
      const float hj = a>0.f? a : expf(a)-1.f;
      contrib += hj*cw[t];
    }
    #pragma unroll
    for (int off=32; off>0; off>>=1) contrib += __shfl_down(contrib, off);
    if (lane==0) orow[0] = contrib + cbp[0];
  }
}

extern "C" void kernel_launch(void* const* d_in, const int* in_sizes, int n_in,
                              void* d_out, int out_size, void* d_ws, size_t ws_size,
                              hipStream_t stream){
  const float* x    =(const float*)d_in[0];
  const int*   ei   =(const int*)d_in[1];
  const float* ea   =(const float*)d_in[2];
  const float* l1w  =(const float*)d_in[3];
  const float* l1b  =(const float*)d_in[4];
  const float* c1rw1=(const float*)d_in[5];
  const float* c1rb1=(const float*)d_in[6];
  const float* c1rw2=(const float*)d_in[7];
  const float* c1rb2=(const float*)d_in[8];
  const float* l2w  =(const float*)d_in[9];
  const float* l2b0 =(const float*)d_in[10];
  const float* l3w  =(const float*)d_in[11];
  const float* l3b0 =(const float*)d_in[12];
  const float* c2rw1=(const float*)d_in[13];
  const float* c2rb1=(const float*)d_in[14];
  const float* c2rw2=(const float*)d_in[15];
  const float* c2rb2=(const float*)d_in[16];
  const float* w40  =(const float*)d_in[17];
  const float* b40  =(const float*)d_in[18];
  const float* w41  =(const float*)d_in[19];
  const float* w42  =(const float*)d_in[20];
  const float* d1w  =(const float*)d_in[21];
  const float* d1b  =(const float*)d_in[22];
  const float* d2w  =(const float*)d_in[23];
  const float* d2b  =(const float*)d_in[24];
  const float* d3w  =(const float*)d_in[25];
  const float* d3b  =(const float*)d_in[26];
  const int N = in_sizes[0]/20;
  const int E = in_sizes[1]/2;
  const int NCA = N/4;
  float* ws = (float*)d_ws;
  int*   wi = (int*)d_ws;
  // zero only the CSR histogram
  hipMemsetAsync(wi + ICNT, 0, (size_t)N*sizeof(int), stream);
  k_setup<<<1,256,0,stream>>>(d2w,d2b,d3w,d3b,ws);
  k_embed<<<(N*40+255)/256,256,0,stream>>>(x,l1w,l1b,ws+FH,N);
  k_cnt <<<(E+255)/256,256,0,stream>>>(ei, wi+ICNT, E);
  k_scan<<<1,256,0,stream>>>(wi+ICNT, wi+IROW, wi+ICUR, N);
  k_scat<<<(E+255)/256,256,0,stream>>>(ei, wi+ICUR, wi+IEID, E);
  k_c1w <<<N,64,0,stream>>>(ei, ea, wi+IROW, wi+IEID,
                            c1rw1,c1rb1,c1rw2,c1rb2, ws+FH,
                            l2w,l2b0,l3w,l3b0, ws+FOUTS);
  k_c2w <<<(NCA+3)/4,256,0,stream>>>(ei, ea, wi+IROW, wi+IEID,
                              c2rw1,c2rb1,c2rw2,c2rb2,
                              ws+FOUTS, ws+OFF_CG, (const int2*)(ws+OFF_DT),
                              w40,b40,w41,w42, d1w,d1b, ws+OFF_CW, ws+OFF_CB,
                              (float*)d_out, NCA);
  (void)n_in; (void)out_size; (void)ws_size;
}

// Round 8
// 2024.263 us; speedup vs baseline: 1.0190x; 1.0190x over previous
//
#include <hip/hip_runtime.h>

#define NPATH 15
#define TOTCG 615
#define TOTD  179

// path tables: PATHS enumeration order of the reference
constexpr int PI_[NPATH]    = {0,0,0,1,1,1,1,1,1,2,2,2,2,2,2};
constexpr int PF_[NPATH]    = {0,1,2,0,1,1,1,2,2,0,1,1,2,2,2};
constexpr int PO_[NPATH]    = {0,1,2,1,0,1,2,1,2,2,1,2,0,1,2};
constexpr int PSLOT_[NPATH] = {0,0,0,1,1,2,1,3,2,3,4,4,2,5,5};
// cumulative size (2i+1)(2f+1)(2o+1)
constexpr int CGOFF_[NPATH] = {0,1,10,35,44,53,80,125,170,245,270,315,390,415,490};
// cumulative size (2i+1)(2o+1)  (D entries)
constexpr int EBASE_[NPATH] = {0,1,4,9,18,21,30,45,54,69,94,109,134,139,154};
// cumulative size (2i+1)(2f+1)  (complex CG tasks)
constexpr int CB_[NPATH]    = {0,1,4,9,12,21,30,39,54,69,74,89,104,129,154};
// acc register layout: cumsum of (2o+1)
constexpr int PACC_[NPATH]  = {0,1,4,9,12,13,16,21,24,29,34,37,42,43,46}; // total 51
// st-concat layout base: O=0 -> S*40 ; O=1 -> 120+S*120 ; O=2 -> 840+S*200
constexpr int STBASE_[NPATH]= {0,120,840,240,40,360,1040,480,1240,1440,600,1640,80,720,1840};

// ws float offsets
#define OFF_CG 0
#define OFF_CW 1024
#define OFF_CB 1280
#define OFF_DT 1536
// int offsets (CSR)
#define ICNT 4096
#define IROW 45056
#define ICUR 86016
#define IEID 126976
// float offsets (big arrays)
#define FH   608256
#define FOUTS 2208256

__device__ inline float sspf(float v){
  float a = fabsf(v);
  return fmaxf(v, 0.f) + log1pf(expf(-a)) - 0.6931471805599453f;
}

__device__ inline double dfact_(int n){ double r=1.0; for(int i=2;i<=n;++i) r*=(double)i; return r; }

__device__ double cgc_(int j1,int j2,int j3,int m1,int m2,int m3){
  double pre = sqrt((2.0*j3+1.0)*dfact_(j1+j2-j3)*dfact_(j1-j2+j3)*dfact_(-j1+j2+j3)/dfact_(j1+j2+j3+1));
  pre *= sqrt(dfact_(j3+m3)*dfact_(j3-m3)*dfact_(j1-m1)*dfact_(j1+m1)*dfact_(j2-m2)*dfact_(j2+m2));
  double s=0.0;
  for(int k=0;k<=j1+j2-j3;++k){
    int d1=j1+j2-j3-k, d2=j1-m1-k, d3=j2+m2-k, d4=j3-j2+m1+k, d5=j3-j1-m2+k;
    if(d1<0||d2<0||d3<0||d4<0||d5<0) continue;
    double den = dfact_(k)*dfact_(d1)*dfact_(d2)*dfact_(d3)*dfact_(d4)*dfact_(d5);
    s += ((k&1)? -1.0:1.0)/den;
  }
  return pre*s;
}

// ---- K0: CG tables (exact replica of _cg_real), D-table, collapsed head linear ----
__global__ __launch_bounds__(256) void k_setup(const float* __restrict__ d2w, const float* __restrict__ d2b,
                        const float* __restrict__ d3w, const float* __restrict__ d3b,
                        float* __restrict__ ws){
  __shared__ double sC[TOTCG], sRe[TOTCG], sIm[TOTCG];
  __shared__ double sUr[35], sUi[35];
  const int tid = threadIdx.x;
  for (int t=tid; t<TOTCG; t+=256) sC[t]=0.0;
  if (tid==0){
    for (int t=0;t<35;t++){ sUr[t]=0.0; sUi[t]=0.0; }
    const double s2 = 0.70710678118654752440;
    sUr[0] = 1.0; // l=0
    for (int l=1;l<=2;l++){
      const int off = (l==1)?1:10;
      const int n = 2*l+1;
      sUr[off + l*n + l] = 1.0;
      for (int m=1;m<=l;m++){
        double sg = (m&1)? -1.0:1.0;
        sUr[off + (l+m)*n + (l+m)] = sg*s2;
        sUi[off + (l+m)*n + (l-m)] = sg*s2;
        sUr[off + (l-m)*n + (l+m)] = s2;
        sUi[off + (l-m)*n + (l-m)] = -s2;
      }
    }
  }
  __syncthreads();
  // phase A: complex-basis CG values
  for (int t=tid; t<179; t+=256){
    int p=0;
    for (int q=1;q<NPATH;q++) if (t>=CB_[q]) p=q;
    const int j1=PI_[p], j2=PF_[p], j3=PO_[p];
    const int n2=2*j2+1, n3=2*j3+1;
    const int loc = t - CB_[p];
    const int i1 = loc/n2, i2 = loc%n2;
    const int m1=i1-j1, m2=i2-j2, m3=m1+m2;
    if (m3>=-j3 && m3<=j3)
      sC[CGOFF_[p] + (i1*n2+i2)*n3 + (m3+j3)] = cgc_(j1,j2,j3,m1,m2,m3);
  }
  __syncthreads();
  // phase C: real transform
  for (int t=tid; t<TOTCG; t+=256){
    int p=0;
    for (int q=1;q<NPATH;q++) if (t>=CGOFF_[q]) p=q;
    const int j1=PI_[p], j2=PF_[p], j3=PO_[p];
    const int n1=2*j1+1, n2=2*j2+1, n3=2*j3+1;
    const int loc = t - CGOFF_[p];
    const int Cc = loc % n3;
    const int Bb = (loc/n3) % n2;
    const int A  = loc/(n3*n2);
    const int u1o = (j1==0)?0:((j1==1)?1:10);
    const int u2o = (j2==0)?0:((j2==1)?1:10);
    const int u3o = (j3==0)?0:((j3==1)?1:10);
    double sre=0.0, sim=0.0;
    for (int a=0;a<n1;a++){
      const double u1r = sUr[u1o + a*n1 + A], u1i = sUi[u1o + a*n1 + A];
      if (u1r==0.0 && u1i==0.0) continue;
      for (int b=0;b<n2;b++){
        const double u2r = sUr[u2o + b*n2 + Bb], u2i = sUi[u2o + b*n2 + Bb];
        if (u2r==0.0 && u2i==0.0) continue;
        const double qr = u1r*u2r - u1i*u2i;
        const double qi = u1r*u2i + u1i*u2r;
        const double* cp = &sC[CGOFF_[p] + (a*n2+b)*n3];
        for (int cidx=0;cidx<n3;cidx++){
          const double v = cp[cidx];
          if (v==0.0) continue;
          const double u3r = sUr[u3o + cidx*n3 + Cc], u3i = -sUi[u3o + cidx*n3 + Cc];
          sre += v*(qr*u3r - qi*u3i);
          sim += v*(qr*u3i + qi*u3r);
        }
      }
    }
    sRe[t]=sre; sIm[t]=sim;
  }
  __syncthreads();
  // phase D: per-path imag/real choice, write to ws
  if (tid < NPATH){
    const int p=tid;
    const int sz = ((p==NPATH-1)? TOTCG : CGOFF_[p+1]) - CGOFF_[p];
    double mxr=0.0, mxi=0.0;
    for (int t=0;t<sz;t++){
      mxr = fmax(mxr, fabs(sRe[CGOFF_[p]+t]));
      mxi = fmax(mxi, fabs(sIm[CGOFF_[p]+t]));
    }
    const bool useim = mxi > mxr;
    for (int t=0;t<sz;t++)
      ws[OFF_CG + CGOFF_[p]+t] = (float)(useim? sIm[CGOFF_[p]+t] : sRe[CGOFF_[p]+t]);
  }
  if (tid==16){
    int2* dt = (int2*)(ws + OFF_DT);
    int e=0;
    for (int p=0;p<NPATH;p++){
      const int i=PI_[p], f=PF_[p], o=PO_[p];
      const int n2=2*f+1, n3=2*o+1;
      for (int mi=0;mi<2*i+1;mi++)
        for (int k=0;k<n3;k++)
          dt[e++] = make_int2(CGOFF_[p] + mi*n2*n3 + k, n2 | (n3<<8) | ((f*f)<<16));
    }
  }
  if (tid<250){
    float acc=0.f;
    for (int k=0;k<150;k++) acc += d3w[k]*d2w[k*250+tid];
    ws[OFF_CW+tid]=acc;
  }
  if (tid==255){
    float acc = d3b[0];
    for (int k=0;k<150;k++) acc += d3w[k]*d2b[k];
    ws[OFF_CB]=acc;
  }
}

// ---- K1: h = x @ lin1_w.T + b ----
__global__ __launch_bounds__(256) void k_embed(const float* __restrict__ x, const float* __restrict__ w,
                       const float* __restrict__ b, float* __restrict__ h, int N){
  const int idx = blockIdx.x*256 + threadIdx.x;
  if (idx >= N*40) return;
  const int n = idx/40, c = idx - n*40;
  float acc = b[c];
  const float* xr = x + (size_t)n*20;
  const float* wr = w + c*20;
  #pragma unroll
  for (int k=0;k<20;k++) acc += xr[k]*wr[k];
  h[idx] = acc;
}

// ---- CSR build: histogram, scan, scatter ----
__global__ __launch_bounds__(256) void k_cnt(const int* __restrict__ ei, int* __restrict__ cnt, int E){
  const int e = blockIdx.x*256 + threadIdx.x;
  if (e < E) atomicAdd(&cnt[ei[E+e]], 1);
}

__global__ __launch_bounds__(256) void k_scan(const int* __restrict__ cnt, int* __restrict__ rowstart,
                                              int* __restrict__ cursor, int N){
  __shared__ int part[256];
  const int tid = threadIdx.x;
  const int per = (N+255)/256;
  const int base = tid*per;
  int s=0;
  for (int i=0;i<per;i++){ const int idx=base+i; if (idx<N) s+=cnt[idx]; }
  part[tid]=s;
  __syncthreads();
  if (tid==0){
    int run=0;
    for (int i=0;i<256;i++){ const int t=part[i]; part[i]=run; run+=t; }
    rowstart[N]=run;
  }
  __syncthreads();
  int run=part[tid];
  for (int i=0;i<per;i++){
    const int idx=base+i;
    if (idx<N){ rowstart[idx]=run; cursor[idx]=run; run+=cnt[idx]; }
  }
}

__global__ __launch_bounds__(256) void k_scat(const int* __restrict__ ei, int* __restrict__ cursor,
                                              int* __restrict__ eids, int E){
  const int e = blockIdx.x*256 + threadIdx.x;
  if (e < E){ const int pos = atomicAdd(&cursor[ei[E+e]], 1); eids[pos]=e; }
}

// ---- K2: fused conv1 (gather) + node transform. ONE WAVE per node, LDS-resident weights. ----
__global__ __launch_bounds__(64) void k_c1w(
    const int* __restrict__ ei, const float* __restrict__ ea,
    const int* __restrict__ rowstart, const int* __restrict__ eids,
    const float* __restrict__ rw1, const float* __restrict__ rb1,
    const float* __restrict__ rw2, const float* __restrict__ rb2,
    const float* __restrict__ h,
    const float* __restrict__ w2g, const float* __restrict__ b20,
    const float* __restrict__ w3g, const float* __restrict__ b30,
    float* __restrict__ outs){
  __shared__ float sRw1T[36*13];   // [task t=l*12+j][bb], row pad 13 -> conflict-free
  __shared__ float sRb1c[36];
  __shared__ float s_h1[36];
  __shared__ float sbuf[360];
  __shared__ float a9[360];
  const int n = blockIdx.x;
  const int lane = threadIdx.x;
  const int c = lane;
  const int r0 = rowstart[n], r1 = rowstart[n+1];
  // stage radial weights once
  for (int u=lane; u<432; u+=64){
    const int t=u/12, bb=u-(u/12)*12;
    const int l=t/12, j=t-(t/12)*12;
    sRw1T[t*13+bb] = rw1[l*144 + bb*12 + j];
  }
  if (lane<36) sRb1c[lane]=rb1[lane];
  float acc[9];
  #pragma unroll
  for (int m=0;m<9;m++) acc[m]=0.f;
  // hoist edge-invariant per-channel weights (reused across ~12 edges)
  float W36[36], base0=0.f, base1=0.f, base2=0.f;
  if (c<40){
    base0=rb2[c]; base1=rb2[40+c]; base2=rb2[80+c];
    #pragma unroll
    for (int t=0;t<36;t++) W36[t]=rw2[t*40+c];
  }
  __syncthreads();
  for (int eb = r0; eb < r1; ++eb){
    const int e = eids[eb];
    const int src = ei[e];
    const float ax=ea[3*e], ay=ea[3*e+1], az=ea[3*e+2];
    const float r = sqrtf(ax*ax+ay*ay+az*az+1e-12f);
    const float inv = 1.f/r;
    const float X=ax*inv, Yv=ay*inv, Z=az*inv;
    if (lane < 36){
      float g[12];
      const float t = r*(11.f/5.f);
      #pragma unroll
      for (int bb=0;bb<12;bb++){ const float d=t-(float)bb; g[bb]=expf(-d*d); }
      float a = sRb1c[lane];
      #pragma unroll
      for (int bb=0;bb<12;bb++) a += g[bb]*sRw1T[lane*13+bb];
      s_h1[lane] = fmaxf(a, 0.f);
    }
    __syncthreads();
    if (c<40){
      float w0=base0, w1=base1, w2=base2;
      #pragma unroll
      for (int j=0;j<12;j++){
        w0 += s_h1[j]    * W36[j];
        w1 += s_h1[12+j] * W36[12+j];
        w2 += s_h1[24+j] * W36[24+j];
      }
      const float hv = h[(size_t)src*40+c];
      acc[0] += hv*w0*0.28209479f;
      const float f1 = hv*w1;
      acc[1]+=f1*(0.48860251f*Yv); acc[2]+=f1*(0.48860251f*Z); acc[3]+=f1*(0.48860251f*X);
      const float f2 = hv*w2;
      acc[4]+=f2*(1.09254843f*X*Yv); acc[5]+=f2*(1.09254843f*Yv*Z);
      acc[6]+=f2*(0.31539157f*(3.f*Z*Z-1.f));
      acc[7]+=f2*(1.09254843f*X*Z); acc[8]+=f2*(0.54627422f*(X*X-Yv*Yv));
    }
    __syncthreads();
  }
  if (c<40){
    #pragma unroll
    for (int m=0;m<9;m++) sbuf[m*40+c]=acc[m];
  }
  __syncthreads();
  // norms per channel
  if (lane<40){
    const int cc=lane;
    const float v0=sbuf[cc];
    sbuf[cc]=v0/(fabsf(v0)+1e-8f);
    float s1=0.f;
    #pragma unroll
    for (int mm=1;mm<4;mm++){ const float v=sbuf[mm*40+cc]; s1+=v*v; }
    const float i1=1.f/(sqrtf(s1)+1e-8f);
    #pragma unroll
    for (int mm=1;mm<4;mm++) sbuf[mm*40+cc]*=i1;
    float s2=0.f;
    #pragma unroll
    for (int mm=4;mm<9;mm++){ const float v=sbuf[mm*40+cc]; s2+=v*v; }
    const float i2=1.f/(sqrtf(s2)+1e-8f);
    #pragma unroll
    for (int mm=4;mm<9;mm++) sbuf[mm*40+cc]*=i2;
  }
  __syncthreads();
  // lin2: 360 outputs (m,o)
  for (int u=lane; u<360; u+=64){
    const int m=u/40, o=u-(u/40)*40;
    const int l=(m==0)?0:((m<4)?1:2);
    const float* wr = w2g + l*1600 + o*40;
    const float* sp = sbuf + m*40;
    float a=0.f;
    for (int c2=0;c2<40;c2++) a+=sp[c2]*wr[c2];
    a9[u]=a;
  }
  __syncthreads();
  // nonlin
  if (lane<40){
    const int o=lane;
    const float a0 = sspf(a9[o]+b20[o]);
    const float n1=sqrtf(a9[40+o]*a9[40+o]+a9[80+o]*a9[80+o]+a9[120+o]*a9[120+o]+1e-12f);
    const float sc1=sspf(n1)/(n1+1e-8f);
    float s2=1e-12f;
    #pragma unroll
    for (int mm=4;mm<9;mm++) s2+=a9[mm*40+o]*a9[mm*40+o];
    const float n2=sqrtf(s2);
    const float sc2=sspf(n2)/(n2+1e-8f);
    a9[o]=a0;
    #pragma unroll
    for (int mm=1;mm<4;mm++) a9[mm*40+o]*=sc1;
    #pragma unroll
    for (int mm=4;mm<9;mm++) a9[mm*40+o]*=sc2;
  }
  __syncthreads();
  // lin3 + write
  float* op = outs + (size_t)n*360;
  for (int u=lane; u<360; u+=64){
    const int m=u/40, o=u-(u/40)*40;
    const int l=(m==0)?0:((m<4)?1:2);
    const float* wr = w3g + l*1600 + o*40;
    const float* sp = a9 + m*40;
    float b=0.f;
    for (int c2=0;c2<40;c2++) b+=sp[c2]*wr[c2];
    if (m==0) b+=b30[o];
    op[u]=b;
  }
}

// ---- K3: fused conv2 (gather) + head. 4 ca-nodes per 256-thread block, one WAVE each. ----
// Shared LDS tables (sW/sB/cgs), wave-private scratch, barrier-free edge loop.
template<int P>
__device__ inline void do_path4(const float* sB, const float* sW,
                               const float* sh1, const float* sD, const float* xi, int c,
                               float* acc){
  constexpr int I = PI_[P], O = PO_[P];
  constexpr int NO = 2*O+1;
  float wp = sB[c*17+P];
  #pragma unroll
  for (int j=0;j<12;j++) wp += sh1[P*12+j]*sW[c*181 + P*12+j];
  float tk[NO];
  #pragma unroll
  for (int k=0;k<NO;k++) tk[k]=0.f;
  #pragma unroll
  for (int mi=0;mi<2*I+1;mi++){
    const float xv = xi[I*I+mi];
    #pragma unroll
    for (int k=0;k<NO;k++) tk[k] += sD[EBASE_[P] + mi*NO + k]*xv;
  }
  #pragma unroll
  for (int k=0;k<NO;k++) acc[PACC_[P]+k] += tk[k]*wp;
}

template<int P>
__device__ inline void st_write(float* dstw, const float* acc, int c){
  constexpr int O = PO_[P];
  constexpr int NO = 2*O+1;
  #pragma unroll
  for (int k=0;k<NO;k++) dstw[STBASE_[P]+k*40+c] = acc[PACC_[P]+k];
}

__global__ __launch_bounds__(256,3) void k_c2w(
    const int* __restrict__ ei, const float* __restrict__ ea,
    const int* __restrict__ rowstart, const int* __restrict__ eids,
    const float* __restrict__ rw1, const float* __restrict__ rb1,
    const float* __restrict__ rw2, const float* __restrict__ rb2,
    const float* __restrict__ outs, const float* __restrict__ cgws, const int2* __restrict__ dtab,
    const float* __restrict__ w40, const float* __restrict__ b40,
    const float* __restrict__ w41, const float* __restrict__ w42,
    const float* __restrict__ d1w, const float* __restrict__ d1b,
    const float* __restrict__ cw, const float* __restrict__ cbp,
    float* __restrict__ out, int NCAv){
  // U: edge phase [sW 7240 | sB 680 | cgs 616] ; head phase: 4x stb[2040]
  __shared__ float U[8536];
  // S: per-wave 380f: edge phase h1[0,180) D[180,364) Y[364,376); head: v1[0,120) v2[120,320) h0[320,360)
  __shared__ float S[1520];
  const int wv = threadIdx.x>>6, lane = threadIdx.x&63, tid = threadIdx.x;
  const int c = lane;
  float* sW = U;
  float* sB = U+7240;
  float* cgs = U+7920;
  for (int u=tid; u<7200; u+=256){ sW[(u%40)*181 + u/40] = rw2[u]; }
  for (int u=tid; u<600;  u+=256){ sB[(u%40)*17  + u/40] = rb2[u]; }
  for (int u=tid; u<615;  u+=256)  cgs[u]=cgws[u];
  __syncthreads();
  const int ca = blockIdx.x*4 + wv;
  const bool okw = ca < NCAv;
  float* s_h1 = S + wv*380;
  float* s_D  = s_h1 + 180;
  float* s_Y  = s_h1 + 364;
  float acc[51];
  #pragma unroll
  for (int i=0;i<51;i++) acc[i]=0.f;
  if (okw){
    const int n = ca*4;
    const int r0 = rowstart[n], r1 = rowstart[n+1];
    for (int eb = r0; eb < r1; ++eb){
      const int e = eids[eb];
      const int src = ei[e];
      const float ax=ea[3*e], ay=ea[3*e+1], az=ea[3*e+2];
      const float r = sqrtf(ax*ax+ay*ay+az*az+1e-12f);
      const float inv = 1.f/r;
      const float X=ax*inv, Yv=ay*inv, Z=az*inv;
      if (lane==0){
        s_Y[0]=0.28209479f;
        s_Y[1]=0.48860251f*Yv; s_Y[2]=0.48860251f*Z; s_Y[3]=0.48860251f*X;
        s_Y[4]=1.09254843f*X*Yv; s_Y[5]=1.09254843f*Yv*Z;
        s_Y[6]=0.31539157f*(3.f*Z*Z-1.f);
        s_Y[7]=1.09254843f*X*Z; s_Y[8]=0.54627422f*(X*X-Yv*Yv);
      }
      if (lane < 60){
        float g[12];
        const float tt = r*(11.f/10.f);
        #pragma unroll
        for (int bb=0;bb<12;bb++){ const float d=tt-(float)bb; g[bb]=expf(-d*d); }
        #pragma unroll
        for (int rr=0;rr<3;rr++){
          const int t = rr*60 + lane;
          const int p = t/12, j = t - (t/12)*12;
          float a = rb1[t];
          #pragma unroll
          for (int bb=0;bb<12;bb++) a += g[bb]*rw1[p*144 + bb*12 + j];
          s_h1[t] = fmaxf(a, 0.f);
        }
      }
      __builtin_amdgcn_wave_barrier();   // intra-wave LDS in program order; hint only
      #pragma unroll
      for (int rr=0;rr<3;rr++){
        const int t = rr*64 + lane;
        if (t < TOTD){
          const int2 dd = dtab[t];
          const int basei = dd.x;
          const int cntv = dd.y & 0xff, str=(dd.y>>8)&0xff, yb=dd.y>>16;
          float a=0.f;
          for (int q=0;q<cntv;q++) a += cgs[basei+q*str]*s_Y[yb+q];
          s_D[t]=a;
        }
      }
      __builtin_amdgcn_wave_barrier();
      if (c<40){
        float xi[9];
        const float* xb = outs + (size_t)src*360 + c;
        #pragma unroll
        for (int mm=0;mm<9;mm++) xi[mm]=xb[mm*40];
#define DP(P) do_path4<P>(sB,sW,s_h1,s_D,xi,c,acc)
        DP(0);DP(1);DP(2);DP(3);DP(4);DP(5);DP(6);DP(7);DP(8);DP(9);DP(10);DP(11);DP(12);DP(13);DP(14);
#undef DP
      }
    }
  }
  __syncthreads();   // all waves done with U tables; reuse region for head tiles
  float* stb = U + wv*2040;
  float* v1s = S + wv*380;
  float* v2s = v1s + 120;
  float* h0s = v1s + 320;
  if (okw){
    if (c<40){
#define SW(P) st_write<P>(stb, acc, c)
      SW(0);SW(1);SW(2);SW(3);SW(4);SW(5);SW(6);SW(7);SW(8);SW(9);SW(10);SW(11);SW(12);SW(13);SW(14);
#undef SW
    }
    __builtin_amdgcn_wave_barrier();
    float* st0 = stb;
    float* st1 = stb+120;
    float* st2 = stb+840;
    // norms: 240 (s,cc) tasks
    for (int t=lane; t<240; t+=64){
      const int s = t/40, cc = t - (t/40)*40;
      float a0=st1[s*120+cc], a1=st1[s*120+40+cc], a2=st1[s*120+80+cc];
      const float i1 = 1.f/(sqrtf(a0*a0+a1*a1+a2*a2)+1e-8f);
      st1[s*120+cc]=a0*i1; st1[s*120+40+cc]=a1*i1; st1[s*120+80+cc]=a2*i1;
      float ss=0.f;
      #pragma unroll
      for (int k=0;k<5;k++){ const float v=st2[s*200+k*40+cc]; ss+=v*v; }
      const float i2 = 1.f/(sqrtf(ss)+1e-8f);
      #pragma unroll
      for (int k=0;k<5;k++) st2[s*200+k*40+cc]*=i2;
    }
    __builtin_amdgcn_wave_barrier();
    for (int t=lane; t<200; t+=64){
      const int o=t/5, k=t-(t/5)*5;
      float a=0.f;
      for (int s=0;s<6;s++){
        const float* sp = st2 + s*200 + k*40;
        const float* wr = w42 + o*240 + s*40;
        #pragma unroll
        for (int cc=0;cc<40;cc++) a += sp[cc]*wr[cc];
      }
      v2s[t]=a;
    }
    for (int t=lane; t<120; t+=64){
      const int o=t/3, k=t-(t/3)*3;
      float a=0.f;
      for (int s=0;s<6;s++){
        const float* sp = st1 + s*120 + k*40;
        const float* wr = w41 + o*240 + s*40;
        #pragma unroll
        for (int cc=0;cc<40;cc++) a += sp[cc]*wr[cc];
      }
      v1s[t]=a;
    }
    if (lane < 40){
      float a = b40[lane];
      const float* wr = w40 + lane*120;
      for (int C=0;C<120;C++) a += st0[C]*wr[C];
      h0s[lane] = sspf(a);
    }
    __builtin_amdgcn_wave_barrier();
    float* orow = out + (size_t)ca*321;
    if (lane < 40){
      const int o=lane;
      const float q0=v1s[o*3],q1=v1s[o*3+1],q2=v1s[o*3+2];
      const float nn=sqrtf(q0*q0+q1*q1+q2*q2+1e-12f);
      const float sc=sspf(nn)/(nn+1e-8f);
      orow[1+o*3]=q0*sc; orow[2+o*3]=q1*sc; orow[3+o*3]=q2*sc;
      // out2 gate for the same o
      float q[5]; float ss=1e-12f;
      #pragma unroll
      for (int k=0;k<5;k++){ q[k]=v2s[o*5+k]; ss+=q[k]*q[k]; }
      const float n2=sqrtf(ss);
      const float sc2=sspf(n2)/(n2+1e-8f);
      #pragma unroll
      for (int k=0;k<5;k++) orow[121+o*5+k]=q[k]*sc2;
    }
    // collapsed MLP: 250 hidden, wave-reduce
    float contrib=0.f;
    for (int t=lane; t<250; t+=64){
      float a=d1b[t];
      const float* wr=d1w+t*40;
      #pragma unroll
      for (int cc=0;cc<40;cc++) a += h0s[cc]*wr[cc];
      const float hj = a>0.f? a : expf(a)-1.f;
      contrib += hj*cw[t];
    }
    #pragma unroll
    for (int off=32; off>0; off>>=1) contrib += __shfl_down(contrib, off);
    if (lane==0) orow[0] = contrib + cbp[0];
  }
}

extern "C" void kernel_launch(void* const* d_in, const int* in_sizes, int n_in,
                              void* d_out, int out_size, void* d_ws, size_t ws_size,
                              hipStream_t stream){
  const float* x    =(const float*)d_in[0];
  const int*   ei   =(const int*)d_in[1];
  const float* ea   =(const float*)d_in[2];
  const float* l1w  =(const float*)d_in[3];
  const float* l1b  =(const float*)d_in[4];
  const float* c1rw1=(const float*)d_in[5];
  const float* c1rb1=(const float*)d_in[6];
  const float* c1rw2=(const float*)d_in[7];
  const float* c1rb2=(const float*)d_in[8];
  const float* l2w  =(const float*)d_in[9];
  const float* l2b0 =(const float*)d_in[10];
  const float* l3w  =(const float*)d_in[11];
  const float* l3b0 =(const float*)d_in[12];
  const float* c2rw1=(const float*)d_in[13];
  const float* c2rb1=(const float*)d_in[14];
  const float* c2rw2=(const float*)d_in[15];
  const float* c2rb2=(const float*)d_in[16];
  const float* w40  =(const float*)d_in[17];
  const float* b40  =(const float*)d_in[18];
  const float* w41  =(const float*)d_in[19];
  const float* w42  =(const float*)d_in[20];
  const float* d1w  =(const float*)d_in[21];
  const float* d1b  =(const float*)d_in[22];
  const float* d2w  =(const float*)d_in[23];
  const float* d2b  =(const float*)d_in[24];
  const float* d3w  =(const float*)d_in[25];
  const float* d3b  =(const float*)d_in[26];
  const int N = in_sizes[0]/20;
  const int E = in_sizes[1]/2;
  const int NCA = N/4;
  float* ws = (float*)d_ws;
  int*   wi = (int*)d_ws;
  // zero only the CSR histogram
  hipMemsetAsync(wi + ICNT, 0, (size_t)N*sizeof(int), stream);
  k_setup<<<1,256,0,stream>>>(d2w,d2b,d3w,d3b,ws);
  k_embed<<<(N*40+255)/256,256,0,stream>>>(x,l1w,l1b,ws+FH,N);
  k_cnt <<<(E+255)/256,256,0,stream>>>(ei, wi+ICNT, E);
  k_scan<<<1,256,0,stream>>>(wi+ICNT, wi+IROW, wi+ICUR, N);
  k_scat<<<(E+255)/256,256,0,stream>>>(ei, wi+ICUR, wi+IEID, E);
  k_c1w <<<N,64,0,stream>>>(ei, ea, wi+IROW, wi+IEID,
                            c1rw1,c1rb1,c1rw2,c1rb2, ws+FH,
                            l2w,l2b0,l3w,l3b0, ws+FOUTS);
  k_c2w <<<(NCA+3)/4,256,0,stream>>>(ei, ea, wi+IROW, wi+IEID,
                              c2rw1,c2rb1,c2rw2,c2rb2,
                              ws+FOUTS, ws+OFF_CG, (const int2*)(ws+OFF_DT),
                              w40,b40,w41,w42, d1w,d1b, ws+OFF_CW, ws+OFF_CB,
                              (float*)d_out, NCA);
  (void)n_in; (void)out_size; (void)ws_size;
}

// Round 9
// 1910.924 us; speedup vs baseline: 1.0794x; 1.0593x over previous
//
#include <hip/hip_runtime.h>

#define NPATH 15
#define TOTCG 615
#define TOTD  179

// path tables: PATHS enumeration order of the reference
constexpr int PI_[NPATH]    = {0,0,0,1,1,1,1,1,1,2,2,2,2,2,2};
constexpr int PF_[NPATH]    = {0,1,2,0,1,1,1,2,2,0,1,1,2,2,2};
constexpr int PO_[NPATH]    = {0,1,2,1,0,1,2,1,2,2,1,2,0,1,2};
constexpr int PSLOT_[NPATH] = {0,0,0,1,1,2,1,3,2,3,4,4,2,5,5};
// cumulative size (2i+1)(2f+1)(2o+1)
constexpr int CGOFF_[NPATH] = {0,1,10,35,44,53,80,125,170,245,270,315,390,415,490};
// cumulative size (2i+1)(2o+1)  (D entries)
constexpr int EBASE_[NPATH] = {0,1,4,9,18,21,30,45,54,69,94,109,134,139,154};
// cumulative size (2i+1)(2f+1)  (complex CG tasks)
constexpr int CB_[NPATH]    = {0,1,4,9,12,21,30,39,54,69,74,89,104,129,154};
// acc register layout: cumsum of (2o+1)
constexpr int PACC_[NPATH]  = {0,1,4,9,12,13,16,21,24,29,34,37,42,43,46}; // total 51
// st-concat layout base: O=0 -> S*40 ; O=1 -> 120+S*120 ; O=2 -> 840+S*200
constexpr int STBASE_[NPATH]= {0,120,840,240,40,360,1040,480,1240,1440,600,1640,80,720,1840};

// ws float offsets
#define OFF_CG 0
#define OFF_CW 1024
#define OFF_CB 1280
#define OFF_DT 1536
// int offsets (CSR)
#define ICNT 4096
#define IROW 45056
#define ICUR 86016
#define IEID 126976
// float offsets (big arrays)
#define FH   608256
#define FOUTS 2208256

__device__ inline float sspf(float v){
  float a = fabsf(v);
  return fmaxf(v, 0.f) + log1pf(expf(-a)) - 0.6931471805599453f;
}

__device__ inline double dfact_(int n){ double r=1.0; for(int i=2;i<=n;++i) r*=(double)i; return r; }

__device__ double cgc_(int j1,int j2,int j3,int m1,int m2,int m3){
  double pre = sqrt((2.0*j3+1.0)*dfact_(j1+j2-j3)*dfact_(j1-j2+j3)*dfact_(-j1+j2+j3)/dfact_(j1+j2+j3+1));
  pre *= sqrt(dfact_(j3+m3)*dfact_(j3-m3)*dfact_(j1-m1)*dfact_(j1+m1)*dfact_(j2-m2)*dfact_(j2+m2));
  double s=0.0;
  for(int k=0;k<=j1+j2-j3;++k){
    int d1=j1+j2-j3-k, d2=j1-m1-k, d3=j2+m2-k, d4=j3-j2+m1+k, d5=j3-j1-m2+k;
    if(d1<0||d2<0||d3<0||d4<0||d5<0) continue;
    double den = dfact_(k)*dfact_(d1)*dfact_(d2)*dfact_(d3)*dfact_(d4)*dfact_(d5);
    s += ((k&1)? -1.0:1.0)/den;
  }
  return pre*s;
}

// ---- K0: CG tables (exact replica of _cg_real), D-table, collapsed head linear ----
__global__ __launch_bounds__(256) void k_setup(const float* __restrict__ d2w, const float* __restrict__ d2b,
                        const float* __restrict__ d3w, const float* __restrict__ d3b,
                        float* __restrict__ ws){
  __shared__ double sC[TOTCG], sRe[TOTCG], sIm[TOTCG];
  __shared__ double sUr[35], sUi[35];
  const int tid = threadIdx.x;
  for (int t=tid; t<TOTCG; t+=256) sC[t]=0.0;
  if (tid==0){
    for (int t=0;t<35;t++){ sUr[t]=0.0; sUi[t]=0.0; }
    const double s2 = 0.70710678118654752440;
    sUr[0] = 1.0; // l=0
    for (int l=1;l<=2;l++){
      const int off = (l==1)?1:10;
      const int n = 2*l+1;
      sUr[off + l*n + l] = 1.0;
      for (int m=1;m<=l;m++){
        double sg = (m&1)? -1.0:1.0;
        sUr[off + (l+m)*n + (l+m)] = sg*s2;
        sUi[off + (l+m)*n + (l-m)] = sg*s2;
        sUr[off + (l-m)*n + (l+m)] = s2;
        sUi[off + (l-m)*n + (l-m)] = -s2;
      }
    }
  }
  __syncthreads();
  // phase A: complex-basis CG values
  for (int t=tid; t<179; t+=256){
    int p=0;
    for (int q=1;q<NPATH;q++) if (t>=CB_[q]) p=q;
    const int j1=PI_[p], j2=PF_[p], j3=PO_[p];
    const int n2=2*j2+1, n3=2*j3+1;
    const int loc = t - CB_[p];
    const int i1 = loc/n2, i2 = loc%n2;
    const int m1=i1-j1, m2=i2-j2, m3=m1+m2;
    if (m3>=-j3 && m3<=j3)
      sC[CGOFF_[p] + (i1*n2+i2)*n3 + (m3+j3)] = cgc_(j1,j2,j3,m1,m2,m3);
  }
  __syncthreads();
  // phase C: real transform
  for (int t=tid; t<TOTCG; t+=256){
    int p=0;
    for (int q=1;q<NPATH;q++) if (t>=CGOFF_[q]) p=q;
    const int j1=PI_[p], j2=PF_[p], j3=PO_[p];
    const int n1=2*j1+1, n2=2*j2+1, n3=2*j3+1;
    const int loc = t - CGOFF_[p];
    const int Cc = loc % n3;
    const int Bb = (loc/n3) % n2;
    const int A  = loc/(n3*n2);
    const int u1o = (j1==0)?0:((j1==1)?1:10);
    const int u2o = (j2==0)?0:((j2==1)?1:10);
    const int u3o = (j3==0)?0:((j3==1)?1:10);
    double sre=0.0, sim=0.0;
    for (int a=0;a<n1;a++){
      const double u1r = sUr[u1o + a*n1 + A], u1i = sUi[u1o + a*n1 + A];
      if (u1r==0.0 && u1i==0.0) continue;
      for (int b=0;b<n2;b++){
        const double u2r = sUr[u2o + b*n2 + Bb], u2i = sUi[u2o + b*n2 + Bb];
        if (u2r==0.0 && u2i==0.0) continue;
        const double qr = u1r*u2r - u1i*u2i;
        const double qi = u1r*u2i + u1i*u2r;
        const double* cp = &sC[CGOFF_[p] + (a*n2+b)*n3];
        for (int cidx=0;cidx<n3;cidx++){
          const double v = cp[cidx];
          if (v==0.0) continue;
          const double u3r = sUr[u3o + cidx*n3 + Cc], u3i = -sUi[u3o + cidx*n3 + Cc];
          sre += v*(qr*u3r - qi*u3i);
          sim += v*(qr*u3i + qi*u3r);
        }
      }
    }
    sRe[t]=sre; sIm[t]=sim;
  }
  __syncthreads();
  // phase D: per-path imag/real choice, write to ws
  if (tid < NPATH){
    const int p=tid;
    const int sz = ((p==NPATH-1)? TOTCG : CGOFF_[p+1]) - CGOFF_[p];
    double mxr=0.0, mxi=0.0;
    for (int t=0;t<sz;t++){
      mxr = fmax(mxr, fabs(sRe[CGOFF_[p]+t]));
      mxi = fmax(mxi, fabs(sIm[CGOFF_[p]+t]));
    }
    const bool useim = mxi > mxr;
    for (int t=0;t<sz;t++)
      ws[OFF_CG + CGOFF_[p]+t] = (float)(useim? sIm[CGOFF_[p]+t] : sRe[CGOFF_[p]+t]);
  }
  if (tid==16){
    int2* dt = (int2*)(ws + OFF_DT);
    int e=0;
    for (int p=0;p<NPATH;p++){
      const int i=PI_[p], f=PF_[p], o=PO_[p];
      const int n2=2*f+1, n3=2*o+1;
      for (int mi=0;mi<2*i+1;mi++)
        for (int k=0;k<n3;k++)
          dt[e++] = make_int2(CGOFF_[p] + mi*n2*n3 + k, n2 | (n3<<8) | ((f*f)<<16));
    }
  }
  if (tid<250){
    float acc=0.f;
    for (int k=0;k<150;k++) acc += d3w[k]*d2w[k*250+tid];
    ws[OFF_CW+tid]=acc;
  }
  if (tid==255){
    float acc = d3b[0];
    for (int k=0;k<150;k++) acc += d3w[k]*d2b[k];
    ws[OFF_CB]=acc;
  }
}

// ---- K1: h = x @ lin1_w.T + b ----
__global__ __launch_bounds__(256) void k_embed(const float* __restrict__ x, const float* __restrict__ w,
                       const float* __restrict__ b, float* __restrict__ h, int N){
  const int idx = blockIdx.x*256 + threadIdx.x;
  if (idx >= N*40) return;
  const int n = idx/40, c = idx - n*40;
  float acc = b[c];
  const float* xr = x + (size_t)n*20;
  const float* wr = w + c*20;
  #pragma unroll
  for (int k=0;k<20;k++) acc += xr[k]*wr[k];
  h[idx] = acc;
}

// ---- CSR build: histogram, scan, scatter ----
__global__ __launch_bounds__(256) void k_cnt(const int* __restrict__ ei, int* __restrict__ cnt, int E){
  const int e = blockIdx.x*256 + threadIdx.x;
  if (e < E) atomicAdd(&cnt[ei[E+e]], 1);
}

__global__ __launch_bounds__(256) void k_scan(const int* __restrict__ cnt, int* __restrict__ rowstart,
                                              int* __restrict__ cursor, int N){
  __shared__ int part[256];
  const int tid = threadIdx.x;
  const int per = (N+255)/256;
  const int base = tid*per;
  int s=0;
  for (int i=0;i<per;i++){ const int idx=base+i; if (idx<N) s+=cnt[idx]; }
  part[tid]=s;
  __syncthreads();
  if (tid==0){
    int run=0;
    for (int i=0;i<256;i++){ const int t=part[i]; part[i]=run; run+=t; }
    rowstart[N]=run;
  }
  __syncthreads();
  int run=part[tid];
  for (int i=0;i<per;i++){
    const int idx=base+i;
    if (idx<N){ rowstart[idx]=run; cursor[idx]=run; run+=cnt[idx]; }
  }
}

__global__ __launch_bounds__(256) void k_scat(const int* __restrict__ ei, int* __restrict__ cursor,
                                              int* __restrict__ eids, int E){
  const int e = blockIdx.x*256 + threadIdx.x;
  if (e < E){ const int pos = atomicAdd(&cursor[ei[E+e]], 1); eids[pos]=e; }
}

// ---- K2: fused conv1 (gather) + node transform. ONE WAVE per node, LDS-resident weights. ----
__global__ __launch_bounds__(64) void k_c1w(
    const int* __restrict__ ei, const float* __restrict__ ea,
    const int* __restrict__ rowstart, const int* __restrict__ eids,
    const float* __restrict__ rw1, const float* __restrict__ rb1,
    const float* __restrict__ rw2, const float* __restrict__ rb2,
    const float* __restrict__ h,
    const float* __restrict__ w2g, const float* __restrict__ b20,
    const float* __restrict__ w3g, const float* __restrict__ b30,
    float* __restrict__ outs){
  __shared__ float sRw1T[36*13];   // [task t=l*12+j][bb], row pad 13 -> conflict-free
  __shared__ float sRb1c[36];
  __shared__ float s_h1[36];
  __shared__ float sbuf[360];
  __shared__ float a9[360];
  const int n = blockIdx.x;
  const int lane = threadIdx.x;
  const int c = lane;
  const int r0 = rowstart[n], r1 = rowstart[n+1];
  // stage radial weights once
  for (int u=lane; u<432; u+=64){
    const int t=u/12, bb=u-(u/12)*12;
    const int l=t/12, j=t-(t/12)*12;
    sRw1T[t*13+bb] = rw1[l*144 + bb*12 + j];
  }
  if (lane<36) sRb1c[lane]=rb1[lane];
  float acc[9];
  #pragma unroll
  for (int m=0;m<9;m++) acc[m]=0.f;
  // hoist edge-invariant per-channel weights (reused across ~12 edges)
  float W36[36], base0=0.f, base1=0.f, base2=0.f;
  if (c<40){
    base0=rb2[c]; base1=rb2[40+c]; base2=rb2[80+c];
    #pragma unroll
    for (int t=0;t<36;t++) W36[t]=rw2[t*40+c];
  }
  __syncthreads();
  for (int eb = r0; eb < r1; ++eb){
    const int e = eids[eb];
    const int src = ei[e];
    const float ax=ea[3*e], ay=ea[3*e+1], az=ea[3*e+2];
    const float r = sqrtf(ax*ax+ay*ay+az*az+1e-12f);
    const float inv = 1.f/r;
    const float X=ax*inv, Yv=ay*inv, Z=az*inv;
    if (lane < 36){
      float g[12];
      const float t = r*(11.f/5.f);
      #pragma unroll
      for (int bb=0;bb<12;bb++){ const float d=t-(float)bb; g[bb]=expf(-d*d); }
      float a = sRb1c[lane];
      #pragma unroll
      for (int bb=0;bb<12;bb++) a += g[bb]*sRw1T[lane*13+bb];
      s_h1[lane] = fmaxf(a, 0.f);
    }
    __syncthreads();
    if (c<40){
      float w0=base0, w1=base1, w2=base2;
      #pragma unroll
      for (int j=0;j<12;j++){
        w0 += s_h1[j]    * W36[j];
        w1 += s_h1[12+j] * W36[12+j];
        w2 += s_h1[24+j] * W36[24+j];
      }
      const float hv = h[(size_t)src*40+c];
      acc[0] += hv*w0*0.28209479f;
      const float f1 = hv*w1;
      acc[1]+=f1*(0.48860251f*Yv); acc[2]+=f1*(0.48860251f*Z); acc[3]+=f1*(0.48860251f*X);
      const float f2 = hv*w2;
      acc[4]+=f2*(1.09254843f*X*Yv); acc[5]+=f2*(1.09254843f*Yv*Z);
      acc[6]+=f2*(0.31539157f*(3.f*Z*Z-1.f));
      acc[7]+=f2*(1.09254843f*X*Z); acc[8]+=f2*(0.54627422f*(X*X-Yv*Yv));
    }
    __syncthreads();
  }
  if (c<40){
    #pragma unroll
    for (int m=0;m<9;m++) sbuf[m*40+c]=acc[m];
  }
  __syncthreads();
  // norms per channel
  if (lane<40){
    const int cc=lane;
    const float v0=sbuf[cc];
    sbuf[cc]=v0/(fabsf(v0)+1e-8f);
    float s1=0.f;
    #pragma unroll
    for (int mm=1;mm<4;mm++){ const float v=sbuf[mm*40+cc]; s1+=v*v; }
    const float i1=1.f/(sqrtf(s1)+1e-8f);
    #pragma unroll
    for (int mm=1;mm<4;mm++) sbuf[mm*40+cc]*=i1;
    float s2=0.f;
    #pragma unroll
    for (int mm=4;mm<9;mm++){ const float v=sbuf[mm*40+cc]; s2+=v*v; }
    const float i2=1.f/(sqrtf(s2)+1e-8f);
    #pragma unroll
    for (int mm=4;mm<9;mm++) sbuf[mm*40+cc]*=i2;
  }
  __syncthreads();
  // lin2: 360 outputs (m,o)
  for (int u=lane; u<360; u+=64){
    const int m=u/40, o=u-(u/40)*40;
    const int l=(m==0)?0:((m<4)?1:2);
    const float* wr = w2g + l*1600 + o*40;
    const float* sp = sbuf + m*40;
    float a=0.f;
    for (int c2=0;c2<40;c2++) a+=sp[c2]*wr[c2];
    a9[u]=a;
  }
  __syncthreads();
  // nonlin
  if (lane<40){
    const int o=lane;
    const float a0 = sspf(a9[o]+b20[o]);
    const float n1=sqrtf(a9[40+o]*a9[40+o]+a9[80+o]*a9[80+o]+a9[120+o]*a9[120+o]+1e-12f);
    const float sc1=sspf(n1)/(n1+1e-8f);
    float s2=1e-12f;
    #pragma unroll
    for (int mm=4;mm<9;mm++) s2+=a9[mm*40+o]*a9[mm*40+o];
    const float n2=sqrtf(s2);
    const float sc2=sspf(n2)/(n2+1e-8f);
    a9[o]=a0;
    #pragma unroll
    for (int mm=1;mm<4;mm++) a9[mm*40+o]*=sc1;
    #pragma unroll
    for (int mm=4;mm<9;mm++) a9[mm*40+o]*=sc2;
  }
  __syncthreads();
  // lin3 + write
  float* op = outs + (size_t)n*360;
  for (int u=lane; u<360; u+=64){
    const int m=u/40, o=u-(u/40)*40;
    const int l=(m==0)?0:((m<4)?1:2);
    const float* wr = w3g + l*1600 + o*40;
    const float* sp = a9 + m*40;
    float b=0.f;
    for (int c2=0;c2<40;c2++) b+=sp[c2]*wr[c2];
    if (m==0) b+=b30[o];
    op[u]=b;
  }
}

// ---- K3: fused conv2 (gather) + head. 4 ca-nodes per 256-thread block, one WAVE each. ----
// Shared LDS tables (sW/sB/cgs), wave-private scratch, barrier-free edge loop.
template<int P>
__device__ inline void do_path4(const float* sB, const float* sW,
                               const float* sh1, const float* sD, const float* xi, int c,
                               float* acc){
  constexpr int I = PI_[P], O = PO_[P];
  constexpr int NO = 2*O+1;
  float wp = sB[c*17+P];
  #pragma unroll
  for (int j=0;j<12;j++) wp += sh1[P*12+j]*sW[c*181 + P*12+j];
  float tk[NO];
  #pragma unroll
  for (int k=0;k<NO;k++) tk[k]=0.f;
  #pragma unroll
  for (int mi=0;mi<2*I+1;mi++){
    const float xv = xi[I*I+mi];
    #pragma unroll
    for (int k=0;k<NO;k++) tk[k] += sD[EBASE_[P] + mi*NO + k]*xv;
  }
  #pragma unroll
  for (int k=0;k<NO;k++) acc[PACC_[P]+k] += tk[k]*wp;
}

template<int P>
__device__ inline void st_write(float* dstw, const float* acc, int c){
  constexpr int O = PO_[P];
  constexpr int NO = 2*O+1;
  #pragma unroll
  for (int k=0;k<NO;k++) dstw[STBASE_[P]+k*40+c] = acc[PACC_[P]+k];
}

__global__ __launch_bounds__(256) void k_c2w(
    const int* __restrict__ ei, const float* __restrict__ ea,
    const int* __restrict__ rowstart, const int* __restrict__ eids,
    const float* __restrict__ rw1, const float* __restrict__ rb1,
    const float* __restrict__ rw2, const float* __restrict__ rb2,
    const float* __restrict__ outs, const float* __restrict__ cgws, const int2* __restrict__ dtab,
    const float* __restrict__ w40, const float* __restrict__ b40,
    const float* __restrict__ w41, const float* __restrict__ w42,
    const float* __restrict__ d1w, const float* __restrict__ d1b,
    const float* __restrict__ cw, const float* __restrict__ cbp,
    float* __restrict__ out, int NCAv){
  // U: edge phase [sW 7240 | sB 680 | cgs 616] ; head phase: 4x stb[2040]
  __shared__ float U[8536];
  // S: per-wave 380f: edge phase h1[0,180) D[180,364) Y[364,376); head: v1[0,120) v2[120,320) h0[320,360)
  __shared__ float S[1520];
  const int wv = threadIdx.x>>6, lane = threadIdx.x&63, tid = threadIdx.x;
  const int c = lane;
  float* sW = U;
  float* sB = U+7240;
  float* cgs = U+7920;
  for (int u=tid; u<7200; u+=256){ sW[(u%40)*181 + u/40] = rw2[u]; }
  for (int u=tid; u<600;  u+=256){ sB[(u%40)*17  + u/40] = rb2[u]; }
  for (int u=tid; u<615;  u+=256)  cgs[u]=cgws[u];
  __syncthreads();
  const int ca = blockIdx.x*4 + wv;
  const bool okw = ca < NCAv;
  float* s_h1 = S + wv*380;
  float* s_D  = s_h1 + 180;
  float* s_Y  = s_h1 + 364;
  float acc[51];
  #pragma unroll
  for (int i=0;i<51;i++) acc[i]=0.f;
  if (okw){
    const int n = ca*4;
    const int r0 = rowstart[n], r1 = rowstart[n+1];
    for (int eb = r0; eb < r1; ++eb){
      const int e = eids[eb];
      const int src = ei[e];
      const float ax=ea[3*e], ay=ea[3*e+1], az=ea[3*e+2];
      const float r = sqrtf(ax*ax+ay*ay+az*az+1e-12f);
      const float inv = 1.f/r;
      const float X=ax*inv, Yv=ay*inv, Z=az*inv;
      if (lane==0){
        s_Y[0]=0.28209479f;
        s_Y[1]=0.48860251f*Yv; s_Y[2]=0.48860251f*Z; s_Y[3]=0.48860251f*X;
        s_Y[4]=1.09254843f*X*Yv; s_Y[5]=1.09254843f*Yv*Z;
        s_Y[6]=0.31539157f*(3.f*Z*Z-1.f);
        s_Y[7]=1.09254843f*X*Z; s_Y[8]=0.54627422f*(X*X-Yv*Yv);
      }
      if (lane < 60){
        float g[12];
        const float tt = r*(11.f/10.f);
        #pragma unroll
        for (int bb=0;bb<12;bb++){ const float d=tt-(float)bb; g[bb]=expf(-d*d); }
        #pragma unroll
        for (int rr=0;rr<3;rr++){
          const int t = rr*60 + lane;
          const int p = t/12, j = t - (t/12)*12;
          float a = rb1[t];
          #pragma unroll
          for (int bb=0;bb<12;bb++) a += g[bb]*rw1[p*144 + bb*12 + j];
          s_h1[t] = fmaxf(a, 0.f);
        }
      }
      __builtin_amdgcn_wave_barrier();   // intra-wave LDS in program order; hint only
      #pragma unroll
      for (int rr=0;rr<3;rr++){
        const int t = rr*64 + lane;
        if (t < TOTD){
          const int2 dd = dtab[t];
          const int basei = dd.x;
          const int cntv = dd.y & 0xff, str=(dd.y>>8)&0xff, yb=dd.y>>16;
          float a=0.f;
          for (int q=0;q<cntv;q++) a += cgs[basei+q*str]*s_Y[yb+q];
          s_D[t]=a;
        }
      }
      __builtin_amdgcn_wave_barrier();
      if (c<40){
        float xi[9];
        const float* xb = outs + (size_t)src*360 + c;
        #pragma unroll
        for (int mm=0;mm<9;mm++) xi[mm]=xb[mm*40];
#define DP(P) do_path4<P>(sB,sW,s_h1,s_D,xi,c,acc)
        DP(0);DP(1);DP(2);DP(3);DP(4);DP(5);DP(6);DP(7);DP(8);DP(9);DP(10);DP(11);DP(12);DP(13);DP(14);
#undef DP
      }
    }
  }
  __syncthreads();   // all waves done with U tables; reuse region for head tiles
  float* stb = U + wv*2040;
  float* v1s = S + wv*380;
  float* v2s = v1s + 120;
  float* h0s = v1s + 320;
  if (okw){
    if (c<40){
#define SW(P) st_write<P>(stb, acc, c)
      SW(0);SW(1);SW(2);SW(3);SW(4);SW(5);SW(6);SW(7);SW(8);SW(9);SW(10);SW(11);SW(12);SW(13);SW(14);
#undef SW
    }
    __builtin_amdgcn_wave_barrier();
    float* st0 = stb;
    float* st1 = stb+120;
    float* st2 = stb+840;
    // norms: 240 (s,cc) tasks
    for (int t=lane; t<240; t+=64){
      const int s = t/40, cc = t - (t/40)*40;
      float a0=st1[s*120+cc], a1=st1[s*120+40+cc], a2=st1[s*120+80+cc];
      const float i1 = 1.f/(sqrtf(a0*a0+a1*a1+a2*a2)+1e-8f);
      st1[s*120+cc]=a0*i1; st1[s*120+40+cc]=a1*i1; st1[s*120+80+cc]=a2*i1;
      float ss=0.f;
      #pragma unroll
      for (int k=0;k<5;k++){ const float v=st2[s*200+k*40+cc]; ss+=v*v; }
      const float i2 = 1.f/(sqrtf(ss)+1e-8f);
      #pragma unroll
      for (int k=0;k<5;k++) st2[s*200+k*40+cc]*=i2;
    }
    __builtin_amdgcn_wave_barrier();
    for (int t=lane; t<200; t+=64){
      const int o=t/5, k=t-(t/5)*5;
      float a=0.f;
      for (int s=0;s<6;s++){
        const float* sp = st2 + s*200 + k*40;
        const float* wr = w42 + o*240 + s*40;
        #pragma unroll
        for (int cc=0;cc<40;cc++) a += sp[cc]*wr[cc];
      }
      v2s[t]=a;
    }
    for (int t=lane; t<120; t+=64){
      const int o=t/3, k=t-(t/3)*3;
      float a=0.f;
      for (int s=0;s<6;s++){
        const float* sp = st1 + s*120 + k*40;
        const float* wr = w41 + o*240 + s*40;
        #pragma unroll
        for (int cc=0;cc<40;cc++) a += sp[cc]*wr[cc];
      }
      v1s[t]=a;
    }
    if (lane < 40){
      float a = b40[lane];
      const float* wr = w40 + lane*120;
      for (int C=0;C<120;C++) a += st0[C]*wr[C];
      h0s[lane] = sspf(a);
    }
    __builtin_amdgcn_wave_barrier();
    float* orow = out + (size_t)ca*321;
    if (lane < 40){
      const int o=lane;
      const float q0=v1s[o*3],q1=v1s[o*3+1],q2=v1s[o*3+2];
      const float nn=sqrtf(q0*q0+q1*q1+q2*q2+1e-12f);
      const float sc=sspf(nn)/(nn+1e-8f);
      orow[1+o*3]=q0*sc; orow[2+o*3]=q1*sc; orow[3+o*3]=q2*sc;
      // out2 gate for the same o
      float q[5]; float ss=1e-12f;
      #pragma unroll
      for (int k=0;k<5;k++){ q[k]=v2s[o*5+k]; ss+=q[k]*q[k]; }
      const float n2=sqrtf(ss);
      const float sc2=sspf(n2)/(n2+1e-8f);
      #pragma unroll
      for (int k=0;k<5;k++) orow[121+o*5+k]=q[k]*sc2;
    }
    // collapsed MLP: 250 hidden, wave-reduce
    float contrib=0.f;
    for (int t=lane; t<250; t+=64){
      float a=d1b[t];
      const float* wr=d1w+t*40;
      #pragma unroll
      for (int cc=0;cc<40;cc++) a += h0s[cc]*wr[cc];
      const float hj = a>0.f? a : expf(a)-1.f;
      contrib += hj*cw[t];
    }
    #pragma unroll
    for (int off=32; off>0; off>>=1) contrib += __shfl_down(contrib, off);
    if (lane==0) orow[0] = contrib + cbp[0];
  }
}

extern "C" void kernel_launch(void* const* d_in, const int* in_sizes, int n_in,
                              void* d_out, int out_size, void* d_ws, size_t ws_size,
                              hipStream_t stream){
  const float* x    =(const float*)d_in[0];
  const int*   ei   =(const int*)d_in[1];
  const float* ea   =(const float*)d_in[2];
  const float* l1w  =(const float*)d_in[3];
  const float* l1b  =(const float*)d_in[4];
  const float* c1rw1=(const float*)d_in[5];
  const float* c1rb1=(const float*)d_in[6];
  const float* c1rw2=(const float*)d_in[7];
  const float* c1rb2=(const float*)d_in[8];
  const float* l2w  =(const float*)d_in[9];
  const float* l2b0 =(const float*)d_in[10];
  const float* l3w  =(const float*)d_in[11];
  const float* l3b0 =(const float*)d_in[12];
  const float* c2rw1=(const float*)d_in[13];
  const float* c2rb1=(const float*)d_in[14];
  const float* c2rw2=(const float*)d_in[15];
  const float* c2rb2=(const float*)d_in[16];
  const float* w40  =(const float*)d_in[17];
  const float* b40  =(const float*)d_in[18];
  const float* w41  =(const float*)d_in[19];
  const float* w42  =(const float*)d_in[20];
  const float* d1w  =(const float*)d_in[21];
  const float* d1b  =(const float*)d_in[22];
  const float* d2w  =(const float*)d_in[23];
  const float* d2b  =(const float*)d_in[24];
  const float* d3w  =(const float*)d_in[25];
  const float* d3b  =(const float*)d_in[26];
  const int N = in_sizes[0]/20;
  const int E = in_sizes[1]/2;
  const int NCA = N/4;
  float* ws = (float*)d_ws;
  int*   wi = (int*)d_ws;
  // zero only the CSR histogram
  hipMemsetAsync(wi + ICNT, 0, (size_t)N*sizeof(int), stream);
  k_setup<<<1,256,0,stream>>>(d2w,d2b,d3w,d3b,ws);
  k_embed<<<(N*40+255)/256,256,0,stream>>>(x,l1w,l1b,ws+FH,N);
  k_cnt <<<(E+255)/256,256,0,stream>>>(ei, wi+ICNT, E);
  k_scan<<<1,256,0,stream>>>(wi+ICNT, wi+IROW, wi+ICUR, N);
  k_scat<<<(E+255)/256,256,0,stream>>>(ei, wi+ICUR, wi+IEID, E);
  k_c1w <<<N,64,0,stream>>>(ei, ea, wi+IROW, wi+IEID,
                            c1rw1,c1rb1,c1rw2,c1rb2, ws+FH,
                            l2w,l2b0,l3w,l3b0, ws+FOUTS);
  k_c2w <<<(NCA+3)/4,256,0,stream>>>(ei, ea, wi+IROW, wi+IEID,
                              c2rw1,c2rb1,c2rw2,c2rb2,
                              ws+FOUTS, ws+OFF_CG, (const int2*)(ws+OFF_DT),
                              w40,b40,w41,w42, d1w,d1b, ws+OFF_CW, ws+OFF_CB,
                              (float*)d_out, NCA);
  (void)n_in; (void)out_size; (void)ws_size;
}

// Round 10
// 1456.845 us; speedup vs baseline: 1.4159x; 1.3117x over previous
//
#include <hip/hip_runtime.h>

#define NPATH 15
#define TOTCG 615
#define TOTD  179

// path tables: PATHS enumeration order of the reference
constexpr int PI_[NPATH]    = {0,0,0,1,1,1,1,1,1,2,2,2,2,2,2};
constexpr int PF_[NPATH]    = {0,1,2,0,1,1,1,2,2,0,1,1,2,2,2};
constexpr int PO_[NPATH]    = {0,1,2,1,0,1,2,1,2,2,1,2,0,1,2};
constexpr int PSLOT_[NPATH] = {0,0,0,1,1,2,1,3,2,3,4,4,2,5,5};
// cumulative size (2i+1)(2f+1)(2o+1)
constexpr int CGOFF_[NPATH] = {0,1,10,35,44,53,80,125,170,245,270,315,390,415,490};
// cumulative size (2i+1)(2o+1)  (D entries)
constexpr int EBASE_[NPATH] = {0,1,4,9,18,21,30,45,54,69,94,109,134,139,154};
// cumulative size (2i+1)(2f+1)  (complex CG tasks)
constexpr int CB_[NPATH]    = {0,1,4,9,12,21,30,39,54,69,74,89,104,129,154};
// acc register layout: cumsum of (2o+1)
constexpr int PACC_[NPATH]  = {0,1,4,9,12,13,16,21,24,29,34,37,42,43,46}; // total 51
// st-concat layout base: O=0 -> S*40 ; O=1 -> 120+S*120 ; O=2 -> 840+S*200
constexpr int STBASE_[NPATH]= {0,120,840,240,40,360,1040,480,1240,1440,600,1640,80,720,1840};

// ws float offsets
#define OFF_CG 0
#define OFF_CW 1024
#define OFF_CB 1280
#define OFF_DT 1536
// int offsets (CSR)
#define ICNT 4096
#define IROW 45056
#define ICUR 86016
#define IEID 126976
// float offsets (big arrays)
#define FH   608256
#define FOUTS 2208256

__device__ inline float sspf(float v){
  float a = fabsf(v);
  return fmaxf(v, 0.f) + log1pf(expf(-a)) - 0.6931471805599453f;
}

__device__ inline double dfact_(int n){ double r=1.0; for(int i=2;i<=n;++i) r*=(double)i; return r; }

__device__ double cgc_(int j1,int j2,int j3,int m1,int m2,int m3){
  double pre = sqrt((2.0*j3+1.0)*dfact_(j1+j2-j3)*dfact_(j1-j2+j3)*dfact_(-j1+j2+j3)/dfact_(j1+j2+j3+1));
  pre *= sqrt(dfact_(j3+m3)*dfact_(j3-m3)*dfact_(j1-m1)*dfact_(j1+m1)*dfact_(j2-m2)*dfact_(j2+m2));
  double s=0.0;
  for(int k=0;k<=j1+j2-j3;++k){
    int d1=j1+j2-j3-k, d2=j1-m1-k, d3=j2+m2-k, d4=j3-j2+m1+k, d5=j3-j1-m2+k;
    if(d1<0||d2<0||d3<0||d4<0||d5<0) continue;
    double den = dfact_(k)*dfact_(d1)*dfact_(d2)*dfact_(d3)*dfact_(d4)*dfact_(d5);
    s += ((k&1)? -1.0:1.0)/den;
  }
  return pre*s;
}

// ---- K0: CG tables (exact replica of _cg_real), D-table, collapsed head linear ----
__global__ __launch_bounds__(256) void k_setup(const float* __restrict__ d2w, const float* __restrict__ d2b,
                        const float* __restrict__ d3w, const float* __restrict__ d3b,
                        float* __restrict__ ws){
  __shared__ double sC[TOTCG], sRe[TOTCG], sIm[TOTCG];
  __shared__ double sUr[35], sUi[35];
  const int tid = threadIdx.x;
  for (int t=tid; t<TOTCG; t+=256) sC[t]=0.0;
  if (tid==0){
    for (int t=0;t<35;t++){ sUr[t]=0.0; sUi[t]=0.0; }
    const double s2 = 0.70710678118654752440;
    sUr[0] = 1.0; // l=0
    for (int l=1;l<=2;l++){
      const int off = (l==1)?1:10;
      const int n = 2*l+1;
      sUr[off + l*n + l] = 1.0;
      for (int m=1;m<=l;m++){
        double sg = (m&1)? -1.0:1.0;
        sUr[off + (l+m)*n + (l+m)] = sg*s2;
        sUi[off + (l+m)*n + (l-m)] = sg*s2;
        sUr[off + (l-m)*n + (l+m)] = s2;
        sUi[off + (l-m)*n + (l-m)] = -s2;
      }
    }
  }
  __syncthreads();
  // phase A: complex-basis CG values
  for (int t=tid; t<179; t+=256){
    int p=0;
    for (int q=1;q<NPATH;q++) if (t>=CB_[q]) p=q;
    const int j1=PI_[p], j2=PF_[p], j3=PO_[p];
    const int n2=2*j2+1, n3=2*j3+1;
    const int loc = t - CB_[p];
    const int i1 = loc/n2, i2 = loc%n2;
    const int m1=i1-j1, m2=i2-j2, m3=m1+m2;
    if (m3>=-j3 && m3<=j3)
      sC[CGOFF_[p] + (i1*n2+i2)*n3 + (m3+j3)] = cgc_(j1,j2,j3,m1,m2,m3);
  }
  __syncthreads();
  // phase C: real transform
  for (int t=tid; t<TOTCG; t+=256){
    int p=0;
    for (int q=1;q<NPATH;q++) if (t>=CGOFF_[q]) p=q;
    const int j1=PI_[p], j2=PF_[p], j3=PO_[p];
    const int n1=2*j1+1, n2=2*j2+1, n3=2*j3+1;
    const int loc = t - CGOFF_[p];
    const int Cc = loc % n3;
    const int Bb = (loc/n3) % n2;
    const int A  = loc/(n3*n2);
    const int u1o = (j1==0)?0:((j1==1)?1:10);
    const int u2o = (j2==0)?0:((j2==1)?1:10);
    const int u3o = (j3==0)?0:((j3==1)?1:10);
    double sre=0.0, sim=0.0;
    for (int a=0;a<n1;a++){
      const double u1r = sUr[u1o + a*n1 + A], u1i = sUi[u1o + a*n1 + A];
      if (u1r==0.0 && u1i==0.0) continue;
      for (int b=0;b<n2;b++){
        const double u2r = sUr[u2o + b*n2 + Bb], u2i = sUi[u2o + b*n2 + Bb];
        if (u2r==0.0 && u2i==0.0) continue;
        const double qr = u1r*u2r - u1i*u2i;
        const double qi = u1r*u2i + u1i*u2r;
        const double* cp = &sC[CGOFF_[p] + (a*n2+b)*n3];
        for (int cidx=0;cidx<n3;cidx++){
          const double v = cp[cidx];
          if (v==0.0) continue;
          const double u3r = sUr[u3o + cidx*n3 + Cc], u3i = -sUi[u3o + cidx*n3 + Cc];
          sre += v*(qr*u3r - qi*u3i);
          sim += v*(qr*u3i + qi*u3r);
        }
      }
    }
    sRe[t]=sre; sIm[t]=sim;
  }
  __syncthreads();
  // phase D: per-path imag/real choice, write to ws
  if (tid < NPATH){
    const int p=tid;
    const int sz = ((p==NPATH-1)? TOTCG : CGOFF_[p+1]) - CGOFF_[p];
    double mxr=0.0, mxi=0.0;
    for (int t=0;t<sz;t++){
      mxr = fmax(mxr, fabs(sRe[CGOFF_[p]+t]));
      mxi = fmax(mxi, fabs(sIm[CGOFF_[p]+t]));
    }
    const bool useim = mxi > mxr;
    for (int t=0;t<sz;t++)
      ws[OFF_CG + CGOFF_[p]+t] = (float)(useim? sIm[CGOFF_[p]+t] : sRe[CGOFF_[p]+t]);
  }
  if (tid==16){
    int2* dt = (int2*)(ws + OFF_DT);
    int e=0;
    for (int p=0;p<NPATH;p++){
      const int i=PI_[p], f=PF_[p], o=PO_[p];
      const int n2=2*f+1, n3=2*o+1;
      for (int mi=0;mi<2*i+1;mi++)
        for (int k=0;k<n3;k++)
          dt[e++] = make_int2(CGOFF_[p] + mi*n2*n3 + k, n2 | (n3<<8) | ((f*f)<<16));
    }
  }
  if (tid<250){
    float acc=0.f;
    for (int k=0;k<150;k++) acc += d3w[k]*d2w[k*250+tid];
    ws[OFF_CW+tid]=acc;
  }
  if (tid==255){
    float acc = d3b[0];
    for (int k=0;k<150;k++) acc += d3w[k]*d2b[k];
    ws[OFF_CB]=acc;
  }
}

// ---- K1: h = x @ lin1_w.T + b ----
__global__ __launch_bounds__(256) void k_embed(const float* __restrict__ x, const float* __restrict__ w,
                       const float* __restrict__ b, float* __restrict__ h, int N){
  const int idx = blockIdx.x*256 + threadIdx.x;
  if (idx >= N*40) return;
  const int n = idx/40, c = idx - n*40;
  float acc = b[c];
  const float* xr = x + (size_t)n*20;
  const float* wr = w + c*20;
  #pragma unroll
  for (int k=0;k<20;k++) acc += xr[k]*wr[k];
  h[idx] = acc;
}

// ---- CSR build: histogram, scan, scatter ----
__global__ __launch_bounds__(256) void k_cnt(const int* __restrict__ ei, int* __restrict__ cnt, int E){
  const int e = blockIdx.x*256 + threadIdx.x;
  if (e < E) atomicAdd(&cnt[ei[E+e]], 1);
}

__global__ __launch_bounds__(256) void k_scan(const int* __restrict__ cnt, int* __restrict__ rowstart,
                                              int* __restrict__ cursor, int N){
  __shared__ int part[256];
  const int tid = threadIdx.x;
  const int per = (N+255)/256;
  const int base = tid*per;
  int s=0;
  for (int i=0;i<per;i++){ const int idx=base+i; if (idx<N) s+=cnt[idx]; }
  part[tid]=s;
  __syncthreads();
  if (tid==0){
    int run=0;
    for (int i=0;i<256;i++){ const int t=part[i]; part[i]=run; run+=t; }
    rowstart[N]=run;
  }
  __syncthreads();
  int run=part[tid];
  for (int i=0;i<per;i++){
    const int idx=base+i;
    if (idx<N){ rowstart[idx]=run; cursor[idx]=run; run+=cnt[idx]; }
  }
}

__global__ __launch_bounds__(256) void k_scat(const int* __restrict__ ei, int* __restrict__ cursor,
                                              int* __restrict__ eids, int E){
  const int e = blockIdx.x*256 + threadIdx.x;
  if (e < E){ const int pos = atomicAdd(&cursor[ei[E+e]], 1); eids[pos]=e; }
}

// ---- K2: fused conv1 (gather) + node transform. ONE WAVE per node, LDS-resident weights. ----
__global__ __launch_bounds__(64) void k_c1w(
    const int* __restrict__ ei, const float* __restrict__ ea,
    const int* __restrict__ rowstart, const int* __restrict__ eids,
    const float* __restrict__ rw1, const float* __restrict__ rb1,
    const float* __restrict__ rw2, const float* __restrict__ rb2,
    const float* __restrict__ h,
    const float* __restrict__ w2g, const float* __restrict__ b20,
    const float* __restrict__ w3g, const float* __restrict__ b30,
    float* __restrict__ outs){
  __shared__ float sRw1T[36*13];   // [task t=l*12+j][bb], row pad 13 -> conflict-free
  __shared__ float sRb1c[36];
  __shared__ float s_h1[36];
  __shared__ float sbuf[360];
  __shared__ float a9[360];
  const int n = blockIdx.x;
  const int lane = threadIdx.x;
  const int c = lane;
  const int r0 = rowstart[n], r1 = rowstart[n+1];
  // stage radial weights once
  for (int u=lane; u<432; u+=64){
    const int t=u/12, bb=u-(u/12)*12;
    const int l=t/12, j=t-(t/12)*12;
    sRw1T[t*13+bb] = rw1[l*144 + bb*12 + j];
  }
  if (lane<36) sRb1c[lane]=rb1[lane];
  float acc[9];
  #pragma unroll
  for (int m=0;m<9;m++) acc[m]=0.f;
  // hoist edge-invariant per-channel weights (reused across ~12 edges)
  float W36[36], base0=0.f, base1=0.f, base2=0.f;
  if (c<40){
    base0=rb2[c]; base1=rb2[40+c]; base2=rb2[80+c];
    #pragma unroll
    for (int t=0;t<36;t++) W36[t]=rw2[t*40+c];
  }
  __syncthreads();
  for (int eb = r0; eb < r1; ++eb){
    const int e = eids[eb];
    const int src = ei[e];
    const float ax=ea[3*e], ay=ea[3*e+1], az=ea[3*e+2];
    const float r = sqrtf(ax*ax+ay*ay+az*az+1e-12f);
    const float inv = 1.f/r;
    const float X=ax*inv, Yv=ay*inv, Z=az*inv;
    if (lane < 36){
      float g[12];
      const float t = r*(11.f/5.f);
      #pragma unroll
      for (int bb=0;bb<12;bb++){ const float d=t-(float)bb; g[bb]=expf(-d*d); }
      float a = sRb1c[lane];
      #pragma unroll
      for (int bb=0;bb<12;bb++) a += g[bb]*sRw1T[lane*13+bb];
      s_h1[lane] = fmaxf(a, 0.f);
    }
    __syncthreads();
    if (c<40){
      float w0=base0, w1=base1, w2=base2;
      #pragma unroll
      for (int j=0;j<12;j++){
        w0 += s_h1[j]    * W36[j];
        w1 += s_h1[12+j] * W36[12+j];
        w2 += s_h1[24+j] * W36[24+j];
      }
      const float hv = h[(size_t)src*40+c];
      acc[0] += hv*w0*0.28209479f;
      const float f1 = hv*w1;
      acc[1]+=f1*(0.48860251f*Yv); acc[2]+=f1*(0.48860251f*Z); acc[3]+=f1*(0.48860251f*X);
      const float f2 = hv*w2;
      acc[4]+=f2*(1.09254843f*X*Yv); acc[5]+=f2*(1.09254843f*Yv*Z);
      acc[6]+=f2*(0.31539157f*(3.f*Z*Z-1.f));
      acc[7]+=f2*(1.09254843f*X*Z); acc[8]+=f2*(0.54627422f*(X*X-Yv*Yv));
    }
    __syncthreads();
  }
  if (c<40){
    #pragma unroll
    for (int m=0;m<9;m++) sbuf[m*40+c]=acc[m];
  }
  __syncthreads();
  // norms per channel
  if (lane<40){
    const int cc=lane;
    const float v0=sbuf[cc];
    sbuf[cc]=v0/(fabsf(v0)+1e-8f);
    float s1=0.f;
    #pragma unroll
    for (int mm=1;mm<4;mm++){ const float v=sbuf[mm*40+cc]; s1+=v*v; }
    const float i1=1.f/(sqrtf(s1)+1e-8f);
    #pragma unroll
    for (int mm=1;mm<4;mm++) sbuf[mm*40+cc]*=i1;
    float s2=0.f;
    #pragma unroll
    for (int mm=4;mm<9;mm++){ const float v=sbuf[mm*40+cc]; s2+=v*v; }
    const float i2=1.f/(sqrtf(s2)+1e-8f);
    #pragma unroll
    for (int mm=4;mm<9;mm++) sbuf[mm*40+cc]*=i2;
  }
  __syncthreads();
  // lin2: 360 outputs (m,o)
  for (int u=lane; u<360; u+=64){
    const int m=u/40, o=u-(u/40)*40;
    const int l=(m==0)?0:((m<4)?1:2);
    const float* wr = w2g + l*1600 + o*40;
    const float* sp = sbuf + m*40;
    float a=0.f;
    for (int c2=0;c2<40;c2++) a+=sp[c2]*wr[c2];
    a9[u]=a;
  }
  __syncthreads();
  // nonlin
  if (lane<40){
    const int o=lane;
    const float a0 = sspf(a9[o]+b20[o]);
    const float n1=sqrtf(a9[40+o]*a9[40+o]+a9[80+o]*a9[80+o]+a9[120+o]*a9[120+o]+1e-12f);
    const float sc1=sspf(n1)/(n1+1e-8f);
    float s2=1e-12f;
    #pragma unroll
    for (int mm=4;mm<9;mm++) s2+=a9[mm*40+o]*a9[mm*40+o];
    const float n2=sqrtf(s2);
    const float sc2=sspf(n2)/(n2+1e-8f);
    a9[o]=a0;
    #pragma unroll
    for (int mm=1;mm<4;mm++) a9[mm*40+o]*=sc1;
    #pragma unroll
    for (int mm=4;mm<9;mm++) a9[mm*40+o]*=sc2;
  }
  __syncthreads();
  // lin3 + write
  float* op = outs + (size_t)n*360;
  for (int u=lane; u<360; u+=64){
    const int m=u/40, o=u-(u/40)*40;
    const int l=(m==0)?0:((m<4)?1:2);
    const float* wr = w3g + l*1600 + o*40;
    const float* sp = a9 + m*40;
    float b=0.f;
    for (int c2=0;c2<40;c2++) b+=sp[c2]*wr[c2];
    if (m==0) b+=b30[o];
    op[u]=b;
  }
}

// ---- K3: fused conv2 (gather) + head. 4 ca-nodes per 256-thread block, one WAVE each. ----
// Shared LDS tables (sW/sB/cgs), wave-private scratch, barrier-free edge loop.
// Paths grouped by input-l I: xiL is a (2I+1)-element group-local array (reduces register pressure).
template<int P>
__device__ inline void do_pathG(const float* sB, const float* sW,
                               const float* sh1, const float* sD, const float* xiL, int c,
                               float* acc){
  constexpr int I = PI_[P], O = PO_[P];
  constexpr int NO = 2*O+1;
  float wp = sB[c*17+P];
  #pragma unroll
  for (int j=0;j<12;j++) wp += sh1[P*12+j]*sW[c*181 + P*12+j];
  float tk[NO];
  #pragma unroll
  for (int k=0;k<NO;k++) tk[k]=0.f;
  #pragma unroll
  for (int mi=0;mi<2*I+1;mi++){
    const float xv = xiL[mi];
    #pragma unroll
    for (int k=0;k<NO;k++) tk[k] += sD[EBASE_[P] + mi*NO + k]*xv;
  }
  #pragma unroll
  for (int k=0;k<NO;k++) acc[PACC_[P]+k] += tk[k]*wp;
}

template<int P>
__device__ inline void st_write(float* dstw, const float* acc, int c){
  constexpr int O = PO_[P];
  constexpr int NO = 2*O+1;
  #pragma unroll
  for (int k=0;k<NO;k++) dstw[STBASE_[P]+k*40+c] = acc[PACC_[P]+k];
}

__global__ __launch_bounds__(256,2) void k_c2w(
    const int* __restrict__ ei, const float* __restrict__ ea,
    const int* __restrict__ rowstart, const int* __restrict__ eids,
    const float* __restrict__ rw1, const float* __restrict__ rb1,
    const float* __restrict__ rw2, const float* __restrict__ rb2,
    const float* __restrict__ outs, const float* __restrict__ cgws, const int2* __restrict__ dtab,
    const float* __restrict__ w40, const float* __restrict__ b40,
    const float* __restrict__ w41, const float* __restrict__ w42,
    const float* __restrict__ d1w, const float* __restrict__ d1b,
    const float* __restrict__ cw, const float* __restrict__ cbp,
    float* __restrict__ out, int NCAv){
  // U: edge phase [sW 7240 | sB 680 | cgs 616] ; head phase: 4x stb[2040]
  __shared__ float U[8536];
  // S: per-wave 380f: edge phase h1[0,180) D[180,364) Y[364,376); head: v1[0,120) v2[120,320) h0[320,360)
  __shared__ float S[1520];
  const int wv = threadIdx.x>>6, lane = threadIdx.x&63, tid = threadIdx.x;
  const int c = lane;
  float* sW = U;
  float* sB = U+7240;
  float* cgs = U+7920;
  for (int u=tid; u<7200; u+=256){ sW[(u%40)*181 + u/40] = rw2[u]; }
  for (int u=tid; u<600;  u+=256){ sB[(u%40)*17  + u/40] = rb2[u]; }
  for (int u=tid; u<615;  u+=256)  cgs[u]=cgws[u];
  __syncthreads();
  const int ca = blockIdx.x*4 + wv;
  const bool okw = ca < NCAv;
  float* s_h1 = S + wv*380;
  float* s_D  = s_h1 + 180;
  float* s_Y  = s_h1 + 364;
  float acc[51];
  #pragma unroll
  for (int i=0;i<51;i++) acc[i]=0.f;
  if (okw){
    const int n = ca*4;
    const int r0 = rowstart[n], r1 = rowstart[n+1];
    for (int eb = r0; eb < r1; ++eb){
      const int e = eids[eb];
      const int src = ei[e];
      const float ax=ea[3*e], ay=ea[3*e+1], az=ea[3*e+2];
      const float r = sqrtf(ax*ax+ay*ay+az*az+1e-12f);
      const float inv = 1.f/r;
      const float X=ax*inv, Yv=ay*inv, Z=az*inv;
      if (lane==0){
        s_Y[0]=0.28209479f;
        s_Y[1]=0.48860251f*Yv; s_Y[2]=0.48860251f*Z; s_Y[3]=0.48860251f*X;
        s_Y[4]=1.09254843f*X*Yv; s_Y[5]=1.09254843f*Yv*Z;
        s_Y[6]=0.31539157f*(3.f*Z*Z-1.f);
        s_Y[7]=1.09254843f*X*Z; s_Y[8]=0.54627422f*(X*X-Yv*Yv);
      }
      if (lane < 60){
        float g[12];
        const float tt = r*(11.f/10.f);
        #pragma unroll
        for (int bb=0;bb<12;bb++){ const float d=tt-(float)bb; g[bb]=expf(-d*d); }
        #pragma unroll
        for (int rr=0;rr<3;rr++){
          const int t = rr*60 + lane;
          const int p = t/12, j = t - (t/12)*12;
          float a = rb1[t];
          #pragma unroll
          for (int bb=0;bb<12;bb++) a += g[bb]*rw1[p*144 + bb*12 + j];
          s_h1[t] = fmaxf(a, 0.f);
        }
      }
      __builtin_amdgcn_wave_barrier();   // intra-wave LDS in program order; hint only
      #pragma unroll
      for (int rr=0;rr<3;rr++){
        const int t = rr*64 + lane;
        if (t < TOTD){
          const int2 dd = dtab[t];
          const int basei = dd.x;
          const int cntv = dd.y & 0xff, str=(dd.y>>8)&0xff, yb=dd.y>>16;
          float a=0.f;
          for (int q=0;q<cntv;q++) a += cgs[basei+q*str]*s_Y[yb+q];
          s_D[t]=a;
        }
      }
      __builtin_amdgcn_wave_barrier();
      if (c<40){
        const float* xb = outs + (size_t)src*360 + c;
        {
          float x0[1]; x0[0]=xb[0];
          do_pathG<0>(sB,sW,s_h1,s_D,x0,c,acc);
          do_pathG<1>(sB,sW,s_h1,s_D,x0,c,acc);
          do_pathG<2>(sB,sW,s_h1,s_D,x0,c,acc);
        }
        {
          float x1[3]; x1[0]=xb[40]; x1[1]=xb[80]; x1[2]=xb[120];
          do_pathG<3>(sB,sW,s_h1,s_D,x1,c,acc);
          do_pathG<4>(sB,sW,s_h1,s_D,x1,c,acc);
          do_pathG<5>(sB,sW,s_h1,s_D,x1,c,acc);
          do_pathG<6>(sB,sW,s_h1,s_D,x1,c,acc);
          do_pathG<7>(sB,sW,s_h1,s_D,x1,c,acc);
          do_pathG<8>(sB,sW,s_h1,s_D,x1,c,acc);
        }
        {
          float x2[5]; x2[0]=xb[160]; x2[1]=xb[200]; x2[2]=xb[240]; x2[3]=xb[280]; x2[4]=xb[320];
          do_pathG<9>(sB,sW,s_h1,s_D,x2,c,acc);
          do_pathG<10>(sB,sW,s_h1,s_D,x2,c,acc);
          do_pathG<11>(sB,sW,s_h1,s_D,x2,c,acc);
          do_pathG<12>(sB,sW,s_h1,s_D,x2,c,acc);
          do_pathG<13>(sB,sW,s_h1,s_D,x2,c,acc);
          do_pathG<14>(sB,sW,s_h1,s_D,x2,c,acc);
        }
      }
    }
  }
  __syncthreads();   // all waves done with U tables; reuse region for head tiles
  float* stb = U + wv*2040;
  float* v1s = S + wv*380;
  float* v2s = v1s + 120;
  float* h0s = v1s + 320;
  if (okw){
    if (c<40){
#define SW(P) st_write<P>(stb, acc, c)
      SW(0);SW(1);SW(2);SW(3);SW(4);SW(5);SW(6);SW(7);SW(8);SW(9);SW(10);SW(11);SW(12);SW(13);SW(14);
#undef SW
    }
    __builtin_amdgcn_wave_barrier();
    float* st0 = stb;
    float* st1 = stb+120;
    float* st2 = stb+840;
    // norms: 240 (s,cc) tasks
    for (int t=lane; t<240; t+=64){
      const int s = t/40, cc = t - (t/40)*40;
      float a0=st1[s*120+cc], a1=st1[s*120+40+cc], a2=st1[s*120+80+cc];
      const float i1 = 1.f/(sqrtf(a0*a0+a1*a1+a2*a2)+1e-8f);
      st1[s*120+cc]=a0*i1; st1[s*120+40+cc]=a1*i1; st1[s*120+80+cc]=a2*i1;
      float ss=0.f;
      #pragma unroll
      for (int k=0;k<5;k++){ const float v=st2[s*200+k*40+cc]; ss+=v*v; }
      const float i2 = 1.f/(sqrtf(ss)+1e-8f);
      #pragma unroll
      for (int k=0;k<5;k++) st2[s*200+k*40+cc]*=i2;
    }
    __builtin_amdgcn_wave_barrier();
    for (int t=lane; t<200; t+=64){
      const int o=t/5, k=t-(t/5)*5;
      float a=0.f;
      for (int s=0;s<6;s++){
        const float* sp = st2 + s*200 + k*40;
        const float* wr = w42 + o*240 + s*40;
        #pragma unroll
        for (int cc=0;cc<40;cc++) a += sp[cc]*wr[cc];
      }
      v2s[t]=a;
    }
    for (int t=lane; t<120; t+=64){
      const int o=t/3, k=t-(t/3)*3;
      float a=0.f;
      for (int s=0;s<6;s++){
        const float* sp = st1 + s*120 + k*40;
        const float* wr = w41 + o*240 + s*40;
        #pragma unroll
        for (int cc=0;cc<40;cc++) a += sp[cc]*wr[cc];
      }
      v1s[t]=a;
    }
    if (lane < 40){
      float a = b40[lane];
      const float* wr = w40 + lane*120;
      for (int C=0;C<120;C++) a += st0[C]*wr[C];
      h0s[lane] = sspf(a);
    }
    __builtin_amdgcn_wave_barrier();
    float* orow = out + (size_t)ca*321;
    if (lane < 40){
      const int o=lane;
      const float q0=v1s[o*3],q1=v1s[o*3+1],q2=v1s[o*3+2];
      const float nn=sqrtf(q0*q0+q1*q1+q2*q2+1e-12f);
      const float sc=sspf(nn)/(nn+1e-8f);
      orow[1+o*3]=q0*sc; orow[2+o*3]=q1*sc; orow[3+o*3]=q2*sc;
      // out2 gate for the same o
      float q[5]; float ss=1e-12f;
      #pragma unroll
      for (int k=0;k<5;k++){ q[k]=v2s[o*5+k]; ss+=q[k]*q[k]; }
      const float n2=sqrtf(ss);
      const float sc2=sspf(n2)/(n2+1e-8f);
      #pragma unroll
      for (int k=0;k<5;k++) orow[121+o*5+k]=q[k]*sc2;
    }
    // collapsed MLP: 250 hidden, wave-reduce
    float contrib=0.f;
    for (int t=lane; t<250; t+=64){
      float a=d1b[t];
      const float* wr=d1w+t*40;
      #pragma unroll
      for (int cc=0;cc<40;cc++) a += h0s[cc]*wr[cc];
      const float hj = a>0.f? a : expf(a)-1.f;
      contrib += hj*cw[t];
    }
    #pragma unroll
    for (int off=32; off>0; off>>=1) contrib += __shfl_down(contrib, off);
    if (lane==0) orow[0] = contrib + cbp[0];
  }
}

extern "C" void kernel_launch(void* const* d_in, const int* in_sizes, int n_in,
                              void* d_out, int out_size, void* d_ws, size_t ws_size,
                              hipStream_t stream){
  const float* x    =(const float*)d_in[0];
  const int*   ei   =(const int*)d_in[1];
  const float* ea   =(const float*)d_in[2];
  const float* l1w  =(const float*)d_in[3];
  const float* l1b  =(const float*)d_in[4];
  const float* c1rw1=(const float*)d_in[5];
  const float* c1rb1=(const float*)d_in[6];
  const float* c1rw2=(const float*)d_in[7];
  const float* c1rb2=(const float*)d_in[8];
  const float* l2w  =(const float*)d_in[9];
  const float* l2b0 =(const float*)d_in[10];
  const float* l3w  =(const float*)d_in[11];
  const float* l3b0 =(const float*)d_in[12];
  const float* c2rw1=(const float*)d_in[13];
  const float* c2rb1=(const float*)d_in[14];
  const float* c2rw2=(const float*)d_in[15];
  const float* c2rb2=(const float*)d_in[16];
  const float* w40  =(const float*)d_in[17];
  const float* b40  =(const float*)d_in[18];
  const float* w41  =(const float*)d_in[19];
  const float* w42  =(const float*)d_in[20];
  const float* d1w  =(const float*)d_in[21];
  const float* d1b  =(const float*)d_in[22];
  const float* d2w  =(const float*)d_in[23];
  const float* d2b  =(const float*)d_in[24];
  const float* d3w  =(const float*)d_in[25];
  const float* d3b  =(const float*)d_in[26];
  const int N = in_sizes[0]/20;
  const int E = in_sizes[1]/2;
  const int NCA = N/4;
  float* ws = (float*)d_ws;
  int*   wi = (int*)d_ws;
  // zero only the CSR histogram
  hipMemsetAsync(wi + ICNT, 0, (size_t)N*sizeof(int), stream);
  k_setup<<<1,256,0,stream>>>(d2w,d2b,d3w,d3b,ws);
  k_embed<<<(N*40+255)/256,256,0,stream>>>(x,l1w,l1b,ws+FH,N);
  k_cnt <<<(E+255)/256,256,0,stream>>>(ei, wi+ICNT, E);
  k_scan<<<1,256,0,stream>>>(wi+ICNT, wi+IROW, wi+ICUR, N);
  k_scat<<<(E+255)/256,256,0,stream>>>(ei, wi+ICUR, wi+IEID, E);
  k_c1w <<<N,64,0,stream>>>(ei, ea, wi+IROW, wi+IEID,
                            c1rw1,c1rb1,c1rw2,c1rb2, ws+FH,
                            l2w,l2b0,l3w,l3b0, ws+FOUTS);
  k_c2w <<<(NCA+3)/4,256,0,stream>>>(ei, ea, wi+IROW, wi+IEID,
                              c2rw1,c2rb1,c2rw2,c2rb2,
                              ws+FOUTS, ws+OFF_CG, (const int2*)(ws+OFF_DT),
                              w40,b40,w41,w42, d1w,d1b, ws+OFF_CW, ws+OFF_CB,
                              (float*)d_out, NCA);
  (void)n_in; (void)out_size; (void)ws_size;
}

// Round 11
// 1346.778 us; speedup vs baseline: 1.5316x; 1.0817x over previous
//
#include <hip/hip_runtime.h>

#define NPATH 15
#define TOTCG 615
#define TOTD  179

// path tables: PATHS enumeration order of the reference
constexpr int PI_[NPATH]    = {0,0,0,1,1,1,1,1,1,2,2,2,2,2,2};
constexpr int PF_[NPATH]    = {0,1,2,0,1,1,1,2,2,0,1,1,2,2,2};
constexpr int PO_[NPATH]    = {0,1,2,1,0,1,2,1,2,2,1,2,0,1,2};
constexpr int PSLOT_[NPATH] = {0,0,0,1,1,2,1,3,2,3,4,4,2,5,5};
// cumulative size (2i+1)(2f+1)(2o+1)
constexpr int CGOFF_[NPATH] = {0,1,10,35,44,53,80,125,170,245,270,315,390,415,490};
// cumulative size (2i+1)(2o+1)  (D entries)
constexpr int EBASE_[NPATH] = {0,1,4,9,18,21,30,45,54,69,94,109,134,139,154};
// cumulative size (2i+1)(2f+1)  (complex CG tasks)
constexpr int CB_[NPATH]    = {0,1,4,9,12,21,30,39,54,69,74,89,104,129,154};
// acc register layout: cumsum of (2o+1)
constexpr int PACC_[NPATH]  = {0,1,4,9,12,13,16,21,24,29,34,37,42,43,46}; // total 51
// st-concat layout base: O=0 -> S*40 ; O=1 -> 120+S*120 ; O=2 -> 840+S*200
constexpr int STBASE_[NPATH]= {0,120,840,240,40,360,1040,480,1240,1440,600,1640,80,720,1840};

// ws float offsets
#define OFF_CG 0
#define OFF_CW 1024
#define OFF_CB 1280
#define OFF_DT 1536
// int offsets (CSR)
#define ICNT 4096
#define IROW 45056
#define ICUR 86016
#define IEID 126976
// float offsets (big arrays)
#define FH   608256
#define FOUTS 2208256

__device__ inline float sspf(float v){
  float a = fabsf(v);
  return fmaxf(v, 0.f) + log1pf(expf(-a)) - 0.6931471805599453f;
}

__device__ inline double dfact_(int n){ double r=1.0; for(int i=2;i<=n;++i) r*=(double)i; return r; }

__device__ double cgc_(int j1,int j2,int j3,int m1,int m2,int m3){
  double pre = sqrt((2.0*j3+1.0)*dfact_(j1+j2-j3)*dfact_(j1-j2+j3)*dfact_(-j1+j2+j3)/dfact_(j1+j2+j3+1));
  pre *= sqrt(dfact_(j3+m3)*dfact_(j3-m3)*dfact_(j1-m1)*dfact_(j1+m1)*dfact_(j2-m2)*dfact_(j2+m2));
  double s=0.0;
  for(int k=0;k<=j1+j2-j3;++k){
    int d1=j1+j2-j3-k, d2=j1-m1-k, d3=j2+m2-k, d4=j3-j2+m1+k, d5=j3-j1-m2+k;
    if(d1<0||d2<0||d3<0||d4<0||d5<0) continue;
    double den = dfact_(k)*dfact_(d1)*dfact_(d2)*dfact_(d3)*dfact_(d4)*dfact_(d5);
    s += ((k&1)? -1.0:1.0)/den;
  }
  return pre*s;
}

// ---- K0: CG tables (exact replica of _cg_real), D-table, collapsed head linear ----
__global__ __launch_bounds__(256) void k_setup(const float* __restrict__ d2w, const float* __restrict__ d2b,
                        const float* __restrict__ d3w, const float* __restrict__ d3b,
                        float* __restrict__ ws){
  __shared__ double sC[TOTCG], sRe[TOTCG], sIm[TOTCG];
  __shared__ double sUr[35], sUi[35];
  const int tid = threadIdx.x;
  for (int t=tid; t<TOTCG; t+=256) sC[t]=0.0;
  if (tid==0){
    for (int t=0;t<35;t++){ sUr[t]=0.0; sUi[t]=0.0; }
    const double s2 = 0.70710678118654752440;
    sUr[0] = 1.0; // l=0
    for (int l=1;l<=2;l++){
      const int off = (l==1)?1:10;
      const int n = 2*l+1;
      sUr[off + l*n + l] = 1.0;
      for (int m=1;m<=l;m++){
        double sg = (m&1)? -1.0:1.0;
        sUr[off + (l+m)*n + (l+m)] = sg*s2;
        sUi[off + (l+m)*n + (l-m)] = sg*s2;
        sUr[off + (l-m)*n + (l+m)] = s2;
        sUi[off + (l-m)*n + (l-m)] = -s2;
      }
    }
  }
  __syncthreads();
  // phase A: complex-basis CG values
  for (int t=tid; t<179; t+=256){
    int p=0;
    for (int q=1;q<NPATH;q++) if (t>=CB_[q]) p=q;
    const int j1=PI_[p], j2=PF_[p], j3=PO_[p];
    const int n2=2*j2+1, n3=2*j3+1;
    const int loc = t - CB_[p];
    const int i1 = loc/n2, i2 = loc%n2;
    const int m1=i1-j1, m2=i2-j2, m3=m1+m2;
    if (m3>=-j3 && m3<=j3)
      sC[CGOFF_[p] + (i1*n2+i2)*n3 + (m3+j3)] = cgc_(j1,j2,j3,m1,m2,m3);
  }
  __syncthreads();
  // phase C: real transform
  for (int t=tid; t<TOTCG; t+=256){
    int p=0;
    for (int q=1;q<NPATH;q++) if (t>=CGOFF_[q]) p=q;
    const int j1=PI_[p], j2=PF_[p], j3=PO_[p];
    const int n1=2*j1+1, n2=2*j2+1, n3=2*j3+1;
    const int loc = t - CGOFF_[p];
    const int Cc = loc % n3;
    const int Bb = (loc/n3) % n2;
    const int A  = loc/(n3*n2);
    const int u1o = (j1==0)?0:((j1==1)?1:10);
    const int u2o = (j2==0)?0:((j2==1)?1:10);
    const int u3o = (j3==0)?0:((j3==1)?1:10);
    double sre=0.0, sim=0.0;
    for (int a=0;a<n1;a++){
      const double u1r = sUr[u1o + a*n1 + A], u1i = sUi[u1o + a*n1 + A];
      if (u1r==0.0 && u1i==0.0) continue;
      for (int b=0;b<n2;b++){
        const double u2r = sUr[u2o + b*n2 + Bb], u2i = sUi[u2o + b*n2 + Bb];
        if (u2r==0.0 && u2i==0.0) continue;
        const double qr = u1r*u2r - u1i*u2i;
        const double qi = u1r*u2i + u1i*u2r;
        const double* cp = &sC[CGOFF_[p] + (a*n2+b)*n3];
        for (int cidx=0;cidx<n3;cidx++){
          const double v = cp[cidx];
          if (v==0.0) continue;
          const double u3r = sUr[u3o + cidx*n3 + Cc], u3i = -sUi[u3o + cidx*n3 + Cc];
          sre += v*(qr*u3r - qi*u3i);
          sim += v*(qr*u3i + qi*u3r);
        }
      }
    }
    sRe[t]=sre; sIm[t]=sim;
  }
  __syncthreads();
  // phase D: per-path imag/real choice, write to ws
  if (tid < NPATH){
    const int p=tid;
    const int sz = ((p==NPATH-1)? TOTCG : CGOFF_[p+1]) - CGOFF_[p];
    double mxr=0.0, mxi=0.0;
    for (int t=0;t<sz;t++){
      mxr = fmax(mxr, fabs(sRe[CGOFF_[p]+t]));
      mxi = fmax(mxi, fabs(sIm[CGOFF_[p]+t]));
    }
    const bool useim = mxi > mxr;
    for (int t=0;t<sz;t++)
      ws[OFF_CG + CGOFF_[p]+t] = (float)(useim? sIm[CGOFF_[p]+t] : sRe[CGOFF_[p]+t]);
  }
  if (tid==16){
    int2* dt = (int2*)(ws + OFF_DT);
    int e=0;
    for (int p=0;p<NPATH;p++){
      const int i=PI_[p], f=PF_[p], o=PO_[p];
      const int n2=2*f+1, n3=2*o+1;
      for (int mi=0;mi<2*i+1;mi++)
        for (int k=0;k<n3;k++)
          dt[e++] = make_int2(CGOFF_[p] + mi*n2*n3 + k, n2 | (n3<<8) | ((f*f)<<16));
    }
  }
  if (tid<250){
    float acc=0.f;
    for (int k=0;k<150;k++) acc += d3w[k]*d2w[k*250+tid];
    ws[OFF_CW+tid]=acc;
  }
  if (tid==255){
    float acc = d3b[0];
    for (int k=0;k<150;k++) acc += d3w[k]*d2b[k];
    ws[OFF_CB]=acc;
  }
}

// ---- K1: h = x @ lin1_w.T + b ----
__global__ __launch_bounds__(256) void k_embed(const float* __restrict__ x, const float* __restrict__ w,
                       const float* __restrict__ b, float* __restrict__ h, int N){
  const int idx = blockIdx.x*256 + threadIdx.x;
  if (idx >= N*40) return;
  const int n = idx/40, c = idx - n*40;
  float acc = b[c];
  const float* xr = x + (size_t)n*20;
  const float* wr = w + c*20;
  #pragma unroll
  for (int k=0;k<20;k++) acc += xr[k]*wr[k];
  h[idx] = acc;
}

// ---- CSR build: histogram, scan, scatter ----
__global__ __launch_bounds__(256) void k_cnt(const int* __restrict__ ei, int* __restrict__ cnt, int E){
  const int e = blockIdx.x*256 + threadIdx.x;
  if (e < E) atomicAdd(&cnt[ei[E+e]], 1);
}

__global__ __launch_bounds__(256) void k_scan(const int* __restrict__ cnt, int* __restrict__ rowstart,
                                              int* __restrict__ cursor, int N){
  __shared__ int part[256];
  const int tid = threadIdx.x;
  const int per = (N+255)/256;
  const int base = tid*per;
  int s=0;
  for (int i=0;i<per;i++){ const int idx=base+i; if (idx<N) s+=cnt[idx]; }
  part[tid]=s;
  __syncthreads();
  if (tid==0){
    int run=0;
    for (int i=0;i<256;i++){ const int t=part[i]; part[i]=run; run+=t; }
    rowstart[N]=run;
  }
  __syncthreads();
  int run=part[tid];
  for (int i=0;i<per;i++){
    const int idx=base+i;
    if (idx<N){ rowstart[idx]=run; cursor[idx]=run; run+=cnt[idx]; }
  }
}

__global__ __launch_bounds__(256) void k_scat(const int* __restrict__ ei, int* __restrict__ cursor,
                                              int* __restrict__ eids, int E){
  const int e = blockIdx.x*256 + threadIdx.x;
  if (e < E){ const int pos = atomicAdd(&cursor[ei[E+e]], 1); eids[pos]=e; }
}

// ---- K2: fused conv1 (gather) + node transform. ONE WAVE per node, LDS-resident weights. ----
__global__ __launch_bounds__(64) void k_c1w(
    const int* __restrict__ ei, const float* __restrict__ ea,
    const int* __restrict__ rowstart, const int* __restrict__ eids,
    const float* __restrict__ rw1, const float* __restrict__ rb1,
    const float* __restrict__ rw2, const float* __restrict__ rb2,
    const float* __restrict__ h,
    const float* __restrict__ w2g, const float* __restrict__ b20,
    const float* __restrict__ w3g, const float* __restrict__ b30,
    float* __restrict__ outs){
  __shared__ float sRw1T[36*13];   // [task t=l*12+j][bb], row pad 13 -> conflict-free
  __shared__ float sRb1c[36];
  __shared__ float s_h1[36];
  __shared__ float sbuf[360];
  __shared__ float a9[360];
  const int n = blockIdx.x;
  const int lane = threadIdx.x;
  const int c = lane;
  const int r0 = rowstart[n], r1 = rowstart[n+1];
  // stage radial weights once
  for (int u=lane; u<432; u+=64){
    const int t=u/12, bb=u-(u/12)*12;
    const int l=t/12, j=t-(t/12)*12;
    sRw1T[t*13+bb] = rw1[l*144 + bb*12 + j];
  }
  if (lane<36) sRb1c[lane]=rb1[lane];
  float acc[9];
  #pragma unroll
  for (int m=0;m<9;m++) acc[m]=0.f;
  // hoist edge-invariant per-channel weights (reused across ~12 edges)
  float W36[36], base0=0.f, base1=0.f, base2=0.f;
  if (c<40){
    base0=rb2[c]; base1=rb2[40+c]; base2=rb2[80+c];
    #pragma unroll
    for (int t=0;t<36;t++) W36[t]=rw2[t*40+c];
  }
  __syncthreads();
  for (int eb = r0; eb < r1; ++eb){
    const int e = eids[eb];
    const int src = ei[e];
    const float ax=ea[3*e], ay=ea[3*e+1], az=ea[3*e+2];
    const float r = sqrtf(ax*ax+ay*ay+az*az+1e-12f);
    const float inv = 1.f/r;
    const float X=ax*inv, Yv=ay*inv, Z=az*inv;
    if (lane < 36){
      float g[12];
      const float t = r*(11.f/5.f);
      #pragma unroll
      for (int bb=0;bb<12;bb++){ const float d=t-(float)bb; g[bb]=expf(-d*d); }
      float a = sRb1c[lane];
      #pragma unroll
      for (int bb=0;bb<12;bb++) a += g[bb]*sRw1T[lane*13+bb];
      s_h1[lane] = fmaxf(a, 0.f);
    }
    __syncthreads();
    if (c<40){
      float w0=base0, w1=base1, w2=base2;
      #pragma unroll
      for (int j=0;j<12;j++){
        w0 += s_h1[j]    * W36[j];
        w1 += s_h1[12+j] * W36[12+j];
        w2 += s_h1[24+j] * W36[24+j];
      }
      const float hv = h[(size_t)src*40+c];
      acc[0] += hv*w0*0.28209479f;
      const float f1 = hv*w1;
      acc[1]+=f1*(0.48860251f*Yv); acc[2]+=f1*(0.48860251f*Z); acc[3]+=f1*(0.48860251f*X);
      const float f2 = hv*w2;
      acc[4]+=f2*(1.09254843f*X*Yv); acc[5]+=f2*(1.09254843f*Yv*Z);
      acc[6]+=f2*(0.31539157f*(3.f*Z*Z-1.f));
      acc[7]+=f2*(1.09254843f*X*Z); acc[8]+=f2*(0.54627422f*(X*X-Yv*Yv));
    }
    __syncthreads();
  }
  if (c<40){
    #pragma unroll
    for (int m=0;m<9;m++) sbuf[m*40+c]=acc[m];
  }
  __syncthreads();
  // norms per channel
  if (lane<40){
    const int cc=lane;
    const float v0=sbuf[cc];
    sbuf[cc]=v0/(fabsf(v0)+1e-8f);
    float s1=0.f;
    #pragma unroll
    for (int mm=1;mm<4;mm++){ const float v=sbuf[mm*40+cc]; s1+=v*v; }
    const float i1=1.f/(sqrtf(s1)+1e-8f);
    #pragma unroll
    for (int mm=1;mm<4;mm++) sbuf[mm*40+cc]*=i1;
    float s2=0.f;
    #pragma unroll
    for (int mm=4;mm<9;mm++){ const float v=sbuf[mm*40+cc]; s2+=v*v; }
    const float i2=1.f/(sqrtf(s2)+1e-8f);
    #pragma unroll
    for (int mm=4;mm<9;mm++) sbuf[mm*40+cc]*=i2;
  }
  __syncthreads();
  // lin2: 360 outputs (m,o)
  for (int u=lane; u<360; u+=64){
    const int m=u/40, o=u-(u/40)*40;
    const int l=(m==0)?0:((m<4)?1:2);
    const float* wr = w2g + l*1600 + o*40;
    const float* sp = sbuf + m*40;
    float a=0.f;
    for (int c2=0;c2<40;c2++) a+=sp[c2]*wr[c2];
    a9[u]=a;
  }
  __syncthreads();
  // nonlin
  if (lane<40){
    const int o=lane;
    const float a0 = sspf(a9[o]+b20[o]);
    const float n1=sqrtf(a9[40+o]*a9[40+o]+a9[80+o]*a9[80+o]+a9[120+o]*a9[120+o]+1e-12f);
    const float sc1=sspf(n1)/(n1+1e-8f);
    float s2=1e-12f;
    #pragma unroll
    for (int mm=4;mm<9;mm++) s2+=a9[mm*40+o]*a9[mm*40+o];
    const float n2=sqrtf(s2);
    const float sc2=sspf(n2)/(n2+1e-8f);
    a9[o]=a0;
    #pragma unroll
    for (int mm=1;mm<4;mm++) a9[mm*40+o]*=sc1;
    #pragma unroll
    for (int mm=4;mm<9;mm++) a9[mm*40+o]*=sc2;
  }
  __syncthreads();
  // lin3 + write
  float* op = outs + (size_t)n*360;
  for (int u=lane; u<360; u+=64){
    const int m=u/40, o=u-(u/40)*40;
    const int l=(m==0)?0:((m<4)?1:2);
    const float* wr = w3g + l*1600 + o*40;
    const float* sp = a9 + m*40;
    float b=0.f;
    for (int c2=0;c2<40;c2++) b+=sp[c2]*wr[c2];
    if (m==0) b+=b30[o];
    op[u]=b;
  }
}

// ---- K3: fused conv2 (gather) + head. 4 ca-nodes per 256-thread block, one WAVE each. ----
// Shared LDS tables (sW b128-strided / sB / cgs / sR1 radial weights), wave-private scratch,
// barrier-free edge loop, dtab hoisted to registers, float4 wp dot-products.
template<int P>
__device__ inline void do_pathV(const float* sB, const float4* sW4, const float4* sh4,
                                const float* sD, const float* xiL, int c, int c47,
                                float* acc){
  constexpr int I = PI_[P], O = PO_[P];
  constexpr int NO = 2*O+1;
  const float4 wa = sW4[c47 + P*3+0];
  const float4 wb = sW4[c47 + P*3+1];
  const float4 wc = sW4[c47 + P*3+2];
  const float4 ha = sh4[P*3+0];
  const float4 hb = sh4[P*3+1];
  const float4 hc = sh4[P*3+2];
  float wp = sB[c*17+P];
  wp += wa.x*ha.x; wp += wa.y*ha.y; wp += wa.z*ha.z; wp += wa.w*ha.w;
  wp += wb.x*hb.x; wp += wb.y*hb.y; wp += wb.z*hb.z; wp += wb.w*hb.w;
  wp += wc.x*hc.x; wp += wc.y*hc.y; wp += wc.z*hc.z; wp += wc.w*hc.w;
  float tk[NO];
  #pragma unroll
  for (int k=0;k<NO;k++) tk[k]=0.f;
  #pragma unroll
  for (int mi=0;mi<2*I+1;mi++){
    const float xv = xiL[mi];
    #pragma unroll
    for (int k=0;k<NO;k++) tk[k] += sD[EBASE_[P] + mi*NO + k]*xv;
  }
  #pragma unroll
  for (int k=0;k<NO;k++) acc[PACC_[P]+k] += tk[k]*wp;
}

template<int P>
__device__ inline void st_write(float* dstw, const float* acc, int c){
  constexpr int O = PO_[P];
  constexpr int NO = 2*O+1;
  #pragma unroll
  for (int k=0;k<NO;k++) dstw[STBASE_[P]+k*40+c] = acc[PACC_[P]+k];
}

__global__ __launch_bounds__(256,2) void k_c2w(
    const int* __restrict__ ei, const float* __restrict__ ea,
    const int* __restrict__ rowstart, const int* __restrict__ eids,
    const float* __restrict__ rw1, const float* __restrict__ rb1,
    const float* __restrict__ rw2, const float* __restrict__ rb2,
    const float* __restrict__ outs, const float* __restrict__ cgws, const int2* __restrict__ dtab,
    const float* __restrict__ w40, const float* __restrict__ b40,
    const float* __restrict__ w41, const float* __restrict__ w42,
    const float* __restrict__ d1w, const float* __restrict__ d1b,
    const float* __restrict__ cw, const float* __restrict__ cbp,
    float* __restrict__ out, int NCAv){
  // U edge phase: sW[0,7520) sB[7520,8200) cgs[8200,8816) sR1[8816,11156) sRb1[11156,11336)
  // U head phase: 4x stb[2040] (<= 8160)
  __shared__ float U[11336];
  // S: per-wave 380f: edge phase h1[0,180) D[180,364) Y[364,376); head: v1[0,120) v2[120,320) h0[320,360)
  __shared__ float S[1520];
  const int wv = threadIdx.x>>6, lane = threadIdx.x&63, tid = threadIdx.x;
  const int c = lane;
  float* sW  = U;            // [c][188] transposed rw2, b128-friendly stride
  float* sB  = U+7520;       // [c][17]  transposed rb2
  float* cgs = U+8200;
  float* sR1 = U+8816;       // [task t][13] transposed rw1
  float* sRb1= U+11156;
  for (int u=tid; u<7200; u+=256){ sW[(u%40)*188 + u/40] = rw2[u]; }
  for (int u=tid; u<600;  u+=256){ sB[(u%40)*17  + u/40] = rb2[u]; }
  for (int u=tid; u<615;  u+=256)  cgs[u]=cgws[u];
  for (int u=tid; u<2160; u+=256){
    const int t=u/12, bb=u-(u/12)*12;
    sR1[t*13+bb] = rw1[(t/12)*144 + bb*12 + (t%12)];
  }
  for (int u=tid; u<180;  u+=256)  sRb1[u]=rb1[u];
  __syncthreads();
  const int ca = blockIdx.x*4 + wv;
  const bool okw = ca < NCAv;
  float* s_h1 = S + wv*380;
  float* s_D  = s_h1 + 180;
  float* s_Y  = s_h1 + 364;
  const float4* sW4 = reinterpret_cast<const float4*>(sW);
  const float4* sh4 = reinterpret_cast<const float4*>(s_h1);
  const int c47 = c*47;
  // hoist edge-invariant dtab rows into registers
  int2 dtr[3];
  #pragma unroll
  for (int rr=0;rr<3;rr++){
    const int t = rr*64 + lane;
    dtr[rr] = (t < TOTD) ? dtab[t] : make_int2(0,0);
  }
  float acc[51];
  #pragma unroll
  for (int i=0;i<51;i++) acc[i]=0.f;
  if (okw){
    const int n = ca*4;
    const int r0 = rowstart[n], r1 = rowstart[n+1];
    for (int eb = r0; eb < r1; ++eb){
      const int e = eids[eb];
      const int src = ei[e];
      const float ax=ea[3*e], ay=ea[3*e+1], az=ea[3*e+2];
      const float r = sqrtf(ax*ax+ay*ay+az*az+1e-12f);
      const float inv = 1.f/r;
      const float X=ax*inv, Yv=ay*inv, Z=az*inv;
      if (lane==0){
        s_Y[0]=0.28209479f;
        s_Y[1]=0.48860251f*Yv; s_Y[2]=0.48860251f*Z; s_Y[3]=0.48860251f*X;
        s_Y[4]=1.09254843f*X*Yv; s_Y[5]=1.09254843f*Yv*Z;
        s_Y[6]=0.31539157f*(3.f*Z*Z-1.f);
        s_Y[7]=1.09254843f*X*Z; s_Y[8]=0.54627422f*(X*X-Yv*Yv);
      }
      if (lane < 60){
        float g[12];
        const float tt = r*(11.f/10.f);
        #pragma unroll
        for (int bb=0;bb<12;bb++){ const float d=tt-(float)bb; g[bb]=expf(-d*d); }
        #pragma unroll
        for (int rr=0;rr<3;rr++){
          const int t = rr*60 + lane;
          float a = sRb1[t];
          #pragma unroll
          for (int bb=0;bb<12;bb++) a += g[bb]*sR1[t*13+bb];
          s_h1[t] = fmaxf(a, 0.f);
        }
      }
      __builtin_amdgcn_wave_barrier();   // intra-wave LDS in program order; hint only
      #pragma unroll
      for (int rr=0;rr<3;rr++){
        const int t = rr*64 + lane;
        if (t < TOTD){
          const int basei = dtr[rr].x;
          const int cntv = dtr[rr].y & 0xff, str=(dtr[rr].y>>8)&0xff, yb=dtr[rr].y>>16;
          float a=0.f;
          for (int q=0;q<cntv;q++) a += cgs[basei+q*str]*s_Y[yb+q];
          s_D[t]=a;
        }
      }
      __builtin_amdgcn_wave_barrier();
      if (c<40){
        const float* xb = outs + (size_t)src*360 + c;
        {
          float x0[1]; x0[0]=xb[0];
          do_pathV<0>(sB,sW4,sh4,s_D,x0,c,c47,acc);
          do_pathV<1>(sB,sW4,sh4,s_D,x0,c,c47,acc);
          do_pathV<2>(sB,sW4,sh4,s_D,x0,c,c47,acc);
        }
        {
          float x1[3]; x1[0]=xb[40]; x1[1]=xb[80]; x1[2]=xb[120];
          do_pathV<3>(sB,sW4,sh4,s_D,x1,c,c47,acc);
          do_pathV<4>(sB,sW4,sh4,s_D,x1,c,c47,acc);
          do_pathV<5>(sB,sW4,sh4,s_D,x1,c,c47,acc);
          do_pathV<6>(sB,sW4,sh4,s_D,x1,c,c47,acc);
          do_pathV<7>(sB,sW4,sh4,s_D,x1,c,c47,acc);
          do_pathV<8>(sB,sW4,sh4,s_D,x1,c,c47,acc);
        }
        {
          float x2[5]; x2[0]=xb[160]; x2[1]=xb[200]; x2[2]=xb[240]; x2[3]=xb[280]; x2[4]=xb[320];
          do_pathV<9>(sB,sW4,sh4,s_D,x2,c,c47,acc);
          do_pathV<10>(sB,sW4,sh4,s_D,x2,c,c47,acc);
          do_pathV<11>(sB,sW4,sh4,s_D,x2,c,c47,acc);
          do_pathV<12>(sB,sW4,sh4,s_D,x2,c,c47,acc);
          do_pathV<13>(sB,sW4,sh4,s_D,x2,c,c47,acc);
          do_pathV<14>(sB,sW4,sh4,s_D,x2,c,c47,acc);
        }
      }
    }
  }
  __syncthreads();   // all waves done with U tables; reuse region for head tiles
  float* stb = U + wv*2040;
  float* v1s = S + wv*380;
  float* v2s = v1s + 120;
  float* h0s = v1s + 320;
  if (okw){
    if (c<40){
#define SW(P) st_write<P>(stb, acc, c)
      SW(0);SW(1);SW(2);SW(3);SW(4);SW(5);SW(6);SW(7);SW(8);SW(9);SW(10);SW(11);SW(12);SW(13);SW(14);
#undef SW
    }
    __builtin_amdgcn_wave_barrier();
    float* st0 = stb;
    float* st1 = stb+120;
    float* st2 = stb+840;
    // norms: 240 (s,cc) tasks
    for (int t=lane; t<240; t+=64){
      const int s = t/40, cc = t - (t/40)*40;
      float a0=st1[s*120+cc], a1=st1[s*120+40+cc], a2=st1[s*120+80+cc];
      const float i1 = 1.f/(sqrtf(a0*a0+a1*a1+a2*a2)+1e-8f);
      st1[s*120+cc]=a0*i1; st1[s*120+40+cc]=a1*i1; st1[s*120+80+cc]=a2*i1;
      float ss=0.f;
      #pragma unroll
      for (int k=0;k<5;k++){ const float v=st2[s*200+k*40+cc]; ss+=v*v; }
      const float i2 = 1.f/(sqrtf(ss)+1e-8f);
      #pragma unroll
      for (int k=0;k<5;k++) st2[s*200+k*40+cc]*=i2;
    }
    __builtin_amdgcn_wave_barrier();
    for (int t=lane; t<200; t+=64){
      const int o=t/5, k=t-(t/5)*5;
      float a=0.f;
      for (int s=0;s<6;s++){
        const float* sp = st2 + s*200 + k*40;
        const float* wr = w42 + o*240 + s*40;
        #pragma unroll
        for (int cc=0;cc<40;cc++) a += sp[cc]*wr[cc];
      }
      v2s[t]=a;
    }
    for (int t=lane; t<120; t+=64){
      const int o=t/3, k=t-(t/3)*3;
      float a=0.f;
      for (int s=0;s<6;s++){
        const float* sp = st1 + s*120 + k*40;
        const float* wr = w41 + o*240 + s*40;
        #pragma unroll
        for (int cc=0;cc<40;cc++) a += sp[cc]*wr[cc];
      }
      v1s[t]=a;
    }
    if (lane < 40){
      float a = b40[lane];
      const float* wr = w40 + lane*120;
      for (int C=0;C<120;C++) a += st0[C]*wr[C];
      h0s[lane] = sspf(a);
    }
    __builtin_amdgcn_wave_barrier();
    float* orow = out + (size_t)ca*321;
    if (lane < 40){
      const int o=lane;
      const float q0=v1s[o*3],q1=v1s[o*3+1],q2=v1s[o*3+2];
      const float nn=sqrtf(q0*q0+q1*q1+q2*q2+1e-12f);
      const float sc=sspf(nn)/(nn+1e-8f);
      orow[1+o*3]=q0*sc; orow[2+o*3]=q1*sc; orow[3+o*3]=q2*sc;
      // out2 gate for the same o
      float q[5]; float ss=1e-12f;
      #pragma unroll
      for (int k=0;k<5;k++){ q[k]=v2s[o*5+k]; ss+=q[k]*q[k]; }
      const float n2=sqrtf(ss);
      const float sc2=sspf(n2)/(n2+1e-8f);
      #pragma unroll
      for (int k=0;k<5;k++) orow[121+o*5+k]=q[k]*sc2;
    }
    // collapsed MLP: 250 hidden, wave-reduce
    float contrib=0.f;
    for (int t=lane; t<250; t+=64){
      float a=d1b[t];
      const float* wr=d1w+t*40;
      #pragma unroll
      for (int cc=0;cc<40;cc++) a += h0s[cc]*wr[cc];
      const float hj = a>0.f? a : expf(a)-1.f;
      contrib += hj*cw[t];
    }
    #pragma unroll
    for (int off=32; off>0; off>>=1) contrib += __shfl_down(contrib, off);
    if (lane==0) orow[0] = contrib + cbp[0];
  }
}

extern "C" void kernel_launch(void* const* d_in, const int* in_sizes, int n_in,
                              void* d_out, int out_size, void* d_ws, size_t ws_size,
                              hipStream_t stream){
  const float* x    =(const float*)d_in[0];
  const int*   ei   =(const int*)d_in[1];
  const float* ea   =(const float*)d_in[2];
  const float* l1w  =(const float*)d_in[3];
  const float* l1b  =(const float*)d_in[4];
  const float* c1rw1=(const float*)d_in[5];
  const float* c1rb1=(const float*)d_in[6];
  const float* c1rw2=(const float*)d_in[7];
  const float* c1rb2=(const float*)d_in[8];
  const float* l2w  =(const float*)d_in[9];
  const float* l2b0 =(const float*)d_in[10];
  const float* l3w  =(const float*)d_in[11];
  const float* l3b0 =(const float*)d_in[12];
  const float* c2rw1=(const float*)d_in[13];
  const float* c2rb1=(const float*)d_in[14];
  const float* c2rw2=(const float*)d_in[15];
  const float* c2rb2=(const float*)d_in[16];
  const float* w40  =(const float*)d_in[17];
  const float* b40  =(const float*)d_in[18];
  const float* w41  =(const float*)d_in[19];
  const float* w42  =(const float*)d_in[20];
  const float* d1w  =(const float*)d_in[21];
  const float* d1b  =(const float*)d_in[22];
  const float* d2w  =(const float*)d_in[23];
  const float* d2b  =(const float*)d_in[24];
  const float* d3w  =(const float*)d_in[25];
  const float* d3b  =(const float*)d_in[26];
  const int N = in_sizes[0]/20;
  const int E = in_sizes[1]/2;
  const int NCA = N/4;
  float* ws = (float*)d_ws;
  int*   wi = (int*)d_ws;
  // zero only the CSR histogram
  hipMemsetAsync(wi + ICNT, 0, (size_t)N*sizeof(int), stream);
  k_setup<<<1,256,0,stream>>>(d2w,d2b,d3w,d3b,ws);
  k_embed<<<(N*40+255)/256,256,0,stream>>>(x,l1w,l1b,ws+FH,N);
  k_cnt <<<(E+255)/256,256,0,stream>>>(ei, wi+ICNT, E);
  k_scan<<<1,256,0,stream>>>(wi+ICNT, wi+IROW, wi+ICUR, N);
  k_scat<<<(E+255)/256,256,0,stream>>>(ei, wi+ICUR, wi+IEID, E);
  k_c1w <<<N,64,0,stream>>>(ei, ea, wi+IROW, wi+IEID,
                            c1rw1,c1rb1,c1rw2,c1rb2, ws+FH,
                            l2w,l2b0,l3w,l3b0, ws+FOUTS);
  k_c2w <<<(NCA+3)/4,256,0,stream>>>(ei, ea, wi+IROW, wi+IEID,
                              c2rw1,c2rb1,c2rw2,c2rb2,
                              ws+FOUTS, ws+OFF_CG, (const int2*)(ws+OFF_DT),
                              w40,b40,w41,w42, d1w,d1b, ws+OFF_CW, ws+OFF_CB,
                              (float*)d_out, NCA);
  (void)n_in; (void)out_size; (void)ws_size;
}